// Round 1
// baseline (1001.047 us; speedup 1.0000x reference)
//
#include <hip/hip_runtime.h>
#include <hip/hip_bf16.h>

// GCN: 3x GCNConv + linear head, fp32, N=100000 nodes, E=800000 edges.
// Identity used: Â(XW) = (ÂX)W  -> aggregate on the narrower side.
//   L1: A=AGG(x[N,128]); h1=relu(A@W1+b1)          (agg width 128)
//   L2: t=h1@W2;          h2=relu(AGG(t)+b2)        (agg width 128)
//   L3: t=h2@W3;          h3=relu(AGG(t)+b3)        (agg width 64)
//   out = h3@Wl + bl
// AGG(v)[i] = dinv[i]*( dinv[i]*v[i] + sum_{src->i} dinv[src]*v[src] )

__global__ __launch_bounds__(256) void hist_kernel(const int* __restrict__ dst,
                                                   int* __restrict__ cnt, int E) {
    int e = blockIdx.x * 256 + threadIdx.x;
    if (e < E) atomicAdd(&cnt[dst[e]], 1);
}

__global__ __launch_bounds__(256) void dinv_kernel(const int* __restrict__ cnt,
                                                   float* __restrict__ dinv, int N) {
    int i = blockIdx.x * 256 + threadIdx.x;
    if (i < N) dinv[i] = rsqrtf((float)cnt[i] + 1.0f);  // +1 self loop
}

// Exclusive scan of cnt[0..N) -> row_ptr[0..N], single block of 1024 threads.
__global__ __launch_bounds__(1024) void scan_kernel(const int* __restrict__ cnt,
                                                    int* __restrict__ row_ptr, int N) {
    const int T = 1024;
    int t = threadIdx.x;
    int chunk = (N + T - 1) / T;
    int lo = t * chunk;
    int hi = lo + chunk; if (hi > N) hi = N;
    int s = 0;
    for (int i = lo; i < hi; ++i) s += cnt[i];
    __shared__ int ps[T];
    ps[t] = s;
    __syncthreads();
    for (int off = 1; off < T; off <<= 1) {
        int v = (t >= off) ? ps[t - off] : 0;
        __syncthreads();
        ps[t] += v;
        __syncthreads();
    }
    int run = (t == 0) ? 0 : ps[t - 1];
    for (int i = lo; i < hi; ++i) { row_ptr[i] = run; run += cnt[i]; }
    if (t == T - 1) row_ptr[N] = run;
}

// Scatter edges into CSR slots. atomicSub slot trick: old in [1..cnt], slot = row_ptr[d+1]-old.
__global__ __launch_bounds__(256) void fill_kernel(const int* __restrict__ src,
                                                   const int* __restrict__ dst,
                                                   const int* __restrict__ row_ptr,
                                                   int* __restrict__ cnt,
                                                   int* __restrict__ csr_src, int E) {
    int e = blockIdx.x * 256 + threadIdx.x;
    if (e < E) {
        int d = dst[e];
        int old = atomicSub(&cnt[d], 1);
        csr_src[row_ptr[d + 1] - old] = src[e];
    }
}

// Gather-aggregate: F threads per node (F>=64 -> degree loop is wave-uniform).
template <int F, bool BIAS_RELU>
__global__ __launch_bounds__(256) void agg_kernel(const float* __restrict__ V,
                                                  const float* __restrict__ dinv,
                                                  const int* __restrict__ row_ptr,
                                                  const int* __restrict__ csr_src,
                                                  const float* __restrict__ bias,
                                                  float* __restrict__ Out, int N) {
    constexpr int SLOTS = 256 / F;
    int f = threadIdx.x % F;
    int slot = threadIdx.x / F;
    int n = blockIdx.x * SLOTS + slot;
    if (n >= N) return;
    float dn = dinv[n];
    float sum = dn * V[(long)n * F + f];          // self-loop term (pre-scaled)
    int e0 = row_ptr[n], e1 = row_ptr[n + 1];
    for (int e = e0; e < e1; ++e) {
        int s = csr_src[e];
        sum += dinv[s] * V[(long)s * F + f];
    }
    float r = dn * sum;
    if constexpr (BIAS_RELU) r = fmaxf(r + bias[f], 0.0f);
    Out[(long)n * F + f] = r;
}

// Register-blocked fp32 GEMM: Y[N,M] = X[N,K] @ W[K,M] (+bias, relu).
// Thread: R=8 rows x C=4 cols. M = CL*4. x-tile in LDS (pad+1, broadcast reads),
// W streamed through L1/L2 (<=128KB, cache-resident).
template <int K, int M, int CL, bool BIAS_RELU>
__global__ __launch_bounds__(256) void gemm_kernel(const float* __restrict__ X,
                                                   const float* __restrict__ W,
                                                   const float* __restrict__ bias,
                                                   float* __restrict__ Y, int N) {
    constexpr int C = 4;
    constexpr int R = 8;
    constexpr int RG = 64 / CL;        // row-groups per wave
    constexpr int ROWS = 4 * RG * R;   // rows per block
    constexpr int KC = 64;             // K-chunk staged in LDS
    __shared__ float xs[ROWS][KC + 1];

    int t = threadIdx.x;
    int wave = t >> 6, lane = t & 63;
    int cl = lane % CL, rg = lane / CL;
    int row_base = (wave * RG + rg) * R;   // thread's first local row
    long block_row0 = (long)blockIdx.x * ROWS;

    float acc[R][C];
#pragma unroll
    for (int i = 0; i < R; ++i)
#pragma unroll
        for (int j = 0; j < C; ++j) acc[i][j] = 0.f;

    for (int kc0 = 0; kc0 < K; kc0 += KC) {
#pragma unroll
        for (int idx = t; idx < ROWS * KC; idx += 256) {
            int r = idx >> 6, k = idx & 63;
            long row = block_row0 + r;
            xs[r][k] = (row < N) ? X[row * K + kc0 + k] : 0.f;
        }
        __syncthreads();
#pragma unroll 4
        for (int k = 0; k < KC; ++k) {
            float wv[C];
#pragma unroll
            for (int j = 0; j < C; ++j) wv[j] = W[(kc0 + k) * M + cl + CL * j];
#pragma unroll
            for (int i = 0; i < R; ++i) {
                float xv = xs[row_base + i][k];
#pragma unroll
                for (int j = 0; j < C; ++j) acc[i][j] += xv * wv[j];
            }
        }
        __syncthreads();
    }
#pragma unroll
    for (int i = 0; i < R; ++i) {
        long row = block_row0 + row_base + i;
        if (row < N) {
#pragma unroll
            for (int j = 0; j < C; ++j) {
                int col = cl + CL * j;
                float v = acc[i][j];
                if constexpr (BIAS_RELU) v = fmaxf(v + bias[col], 0.f);
                Y[row * M + col] = v;
            }
        }
    }
}

// out[n] = dot(h3[n,0:64], Wl) + bl ; one wave per node.
__global__ __launch_bounds__(256) void final_kernel(const float* __restrict__ H,
                                                    const float* __restrict__ Wl,
                                                    const float* __restrict__ bl,
                                                    float* __restrict__ out, int N) {
    int wave = threadIdx.x >> 6, lane = threadIdx.x & 63;
    int n = blockIdx.x * 4 + wave;
    if (n >= N) return;
    float v = H[(long)n * 64 + lane] * Wl[lane];
#pragma unroll
    for (int off = 32; off; off >>= 1) v += __shfl_down(v, off);
    if (lane == 0) out[n] = v + bl[0];
}

extern "C" void kernel_launch(void* const* d_in, const int* in_sizes, int n_in,
                              void* d_out, int out_size, void* d_ws, size_t ws_size,
                              hipStream_t stream) {
    const float* x  = (const float*)d_in[0];
    const int* edge = (const int*)d_in[1];
    const float* W1 = (const float*)d_in[2];
    const float* b1 = (const float*)d_in[3];
    const float* W2 = (const float*)d_in[4];
    const float* b2 = (const float*)d_in[5];
    const float* W3 = (const float*)d_in[6];
    const float* b3 = (const float*)d_in[7];
    const float* Wl = (const float*)d_in[8];
    const float* bl = (const float*)d_in[9];
    float* out = (float*)d_out;

    int N = in_sizes[0] / 128;   // 100000
    int E = in_sizes[1] / 2;     // 800000
    const int* src = edge;
    const int* dst = edge + E;

    char* ws = (char*)d_ws;
    size_t off = 0;
    auto alloc = [&](size_t bytes) {
        void* p = ws + off;
        off += (bytes + 255) & ~(size_t)255;
        return p;
    };
    int*   cnt     = (int*)  alloc((size_t)N * 4);
    int*   row_ptr = (int*)  alloc((size_t)(N + 1) * 4);
    float* dinv    = (float*)alloc((size_t)N * 4);
    int*   csr_src = (int*)  alloc((size_t)E * 4);
    float* B1      = (float*)alloc((size_t)N * 128 * 4);   // narrow ping buffer
    float* B2      = (float*)alloc((size_t)N * 256 * 4);   // wide pong buffer
    (void)ws_size; (void)n_in; (void)out_size;

    // ---- graph preprocessing (per launch; ws is re-poisoned each call) ----
    hipMemsetAsync(cnt, 0, (size_t)N * 4, stream);
    hist_kernel<<<(E + 255) / 256, 256, 0, stream>>>(dst, cnt, E);
    dinv_kernel<<<(N + 255) / 256, 256, 0, stream>>>(cnt, dinv, N);
    scan_kernel<<<1, 1024, 0, stream>>>(cnt, row_ptr, N);
    fill_kernel<<<(E + 255) / 256, 256, 0, stream>>>(src, dst, row_ptr, cnt, csr_src, E);

    // ---- layer 1: aggregate(128) then GEMM 128->256 (+b1, relu) ----
    agg_kernel<128, false><<<N / 2, 256, 0, stream>>>(x, dinv, row_ptr, csr_src, nullptr, B1, N);
    gemm_kernel<128, 256, 64, true><<<(N + 31) / 32, 256, 0, stream>>>(B1, W1, b1, B2, N);

    // ---- layer 2: GEMM 256->128, aggregate(128) (+b2, relu) ----
    gemm_kernel<256, 128, 32, false><<<(N + 63) / 64, 256, 0, stream>>>(B2, W2, nullptr, B1, N);
    agg_kernel<128, true><<<N / 2, 256, 0, stream>>>(B1, dinv, row_ptr, csr_src, b2, B2, N);

    // ---- layer 3: GEMM 128->64, aggregate(64) (+b3, relu) ----
    gemm_kernel<128, 64, 16, false><<<(N + 127) / 128, 256, 0, stream>>>(B2, W3, nullptr, B1, N);
    agg_kernel<64, true><<<(N + 3) / 4, 256, 0, stream>>>(B1, dinv, row_ptr, csr_src, b3, B2, N);

    // ---- head ----
    final_kernel<<<(N + 3) / 4, 256, 0, stream>>>(B2, Wl, bl, out, N);
}

// Round 3
// 605.686 us; speedup vs baseline: 1.6527x; 1.6527x over previous
//
#include <hip/hip_runtime.h>
#include <hip/hip_bf16.h>
#include <stdint.h>

// GCN 3-layer + head, bf16 data path, fp32 accumulate everywhere.
// Identity: Â(XW) = (ÂX)W; aggregate on the narrower side.
// Scaled-space trick: store ṽ = dinv⊙v (bf16). Then
//   agg(v)[i] = d_i*(ṽ_i + Σ_{s->i} ṽ_s), and d>0 commutes with ReLU,
// so the gather loop is a pure row sum (no per-edge dinv load).
// Pipeline:
//   P0:  U0 = bf16(d ⊙ x)                                  [B_a]
//   agg1: A1 = bf16(d_i*(U0_i + ΣU0_s))                    [B_b]
//   G1:  H1 = bf16(relu(A1@W1 + b1))                       [B_c]
//   G2:  U2 = bf16(d ⊙ (H1@W2))                            [B_a]
//   agg2: H2 = bf16(relu(d_i*(U2_i + ΣU2_s) + b2))         [B_b]
//   G3:  U3 = bf16(d ⊙ (H2@W3))                            [B_a]
//   agg3+head: h3 = relu(d_i*(U3_i+ΣU3_s)+b3); out = h3·Wl + bl

typedef __attribute__((ext_vector_type(8))) short bf16x8;
typedef __attribute__((ext_vector_type(16))) float f32x16;

__device__ __forceinline__ float bf_lo(uint32_t u) {
    union { uint32_t i; float f; } v; v.i = u << 16; return v.f;
}
__device__ __forceinline__ float bf_hi(uint32_t u) {
    union { uint32_t i; float f; } v; v.i = u & 0xffff0000u; return v.f;
}
__device__ __forceinline__ float bf_s(uint16_t h) {
    union { uint32_t i; float f; } v; v.i = ((uint32_t)h) << 16; return v.f;
}
__device__ __forceinline__ uint16_t f2bf(float f) {   // RNE
    union { float f; uint32_t i; } v; v.f = f;
    uint32_t r = v.i + 0x7fffu + ((v.i >> 16) & 1u);
    return (uint16_t)(r >> 16);
}
__device__ __forceinline__ uint32_t packbf(float a, float b) {
    return (uint32_t)f2bf(a) | ((uint32_t)f2bf(b) << 16);
}

// ---------------- graph preprocessing ----------------
__global__ __launch_bounds__(256) void hist_kernel(const int* __restrict__ dst,
                                                   int* __restrict__ cnt, int E) {
    int e = blockIdx.x * 256 + threadIdx.x;
    if (e < E) atomicAdd(&cnt[dst[e]], 1);
}

__global__ __launch_bounds__(256) void dinv_kernel(const int* __restrict__ cnt,
                                                   float* __restrict__ dinv, int N) {
    int i = blockIdx.x * 256 + threadIdx.x;
    if (i < N) dinv[i] = rsqrtf((float)cnt[i] + 1.0f);
}

__global__ __launch_bounds__(1024) void scan_kernel(const int* __restrict__ cnt,
                                                    int* __restrict__ row_ptr, int N) {
    const int T = 1024;
    int t = threadIdx.x;
    int chunk = (N + T - 1) / T;
    int lo = t * chunk, hi = lo + chunk; if (hi > N) hi = N;
    int s = 0;
    for (int i = lo; i < hi; ++i) s += cnt[i];
    __shared__ int ps[T];
    ps[t] = s;
    __syncthreads();
    for (int off = 1; off < T; off <<= 1) {
        int v = (t >= off) ? ps[t - off] : 0;
        __syncthreads();
        ps[t] += v;
        __syncthreads();
    }
    int run = (t == 0) ? 0 : ps[t - 1];
    for (int i = lo; i < hi; ++i) { row_ptr[i] = run; run += cnt[i]; }
    if (t == T - 1) row_ptr[N] = run;
}

__global__ __launch_bounds__(256) void fill_kernel(const int* __restrict__ src,
                                                   const int* __restrict__ dst,
                                                   const int* __restrict__ row_ptr,
                                                   int* __restrict__ cnt,
                                                   int* __restrict__ csr_src, int E) {
    int e = blockIdx.x * 256 + threadIdx.x;
    if (e < E) {
        int d = dst[e];
        int old = atomicSub(&cnt[d], 1);
        csr_src[row_ptr[d + 1] - old] = src[e];
    }
}

// ---------------- P0: U0 = bf16(dinv ⊙ x) ----------------
__global__ __launch_bounds__(256) void scale_cvt(const float* __restrict__ x,
                                                 const float* __restrict__ dinv,
                                                 uint32_t* __restrict__ U, long total) {
    long i = (long)blockIdx.x * 256 + threadIdx.x;
    if (i >= total) return;
    int row = (int)(i >> 6);
    float2 v = ((const float2*)x)[i];
    float d = dinv[row];
    U[i] = packbf(d * v.x, d * v.y);
}

// ---------------- aggregation, 128 channels (wave per node, bf16x2/lane) ----------------
template <bool BIAS_RELU>
__global__ __launch_bounds__(256) void agg128(const uint32_t* __restrict__ U,
                                              const float* __restrict__ dinv,
                                              const int* __restrict__ row_ptr,
                                              const int* __restrict__ csr_src,
                                              const float* __restrict__ bias,
                                              uint32_t* __restrict__ Out, int N) {
    int wave = threadIdx.x >> 6, lane = threadIdx.x & 63;
    int n = blockIdx.x * 4 + wave;
    if (n >= N) return;
    uint32_t u = U[(long)n * 64 + lane];
    float s0 = bf_lo(u), s1 = bf_hi(u);
    int e0 = row_ptr[n], e1 = row_ptr[n + 1];
    int e = e0;
    for (; e + 4 <= e1; e += 4) {                 // 4 concurrent gathers (MLP)
        int i0 = csr_src[e], i1 = csr_src[e + 1], i2 = csr_src[e + 2], i3 = csr_src[e + 3];
        uint32_t u0 = U[(long)i0 * 64 + lane];
        uint32_t u1 = U[(long)i1 * 64 + lane];
        uint32_t u2 = U[(long)i2 * 64 + lane];
        uint32_t u3 = U[(long)i3 * 64 + lane];
        s0 += (bf_lo(u0) + bf_lo(u1)) + (bf_lo(u2) + bf_lo(u3));
        s1 += (bf_hi(u0) + bf_hi(u1)) + (bf_hi(u2) + bf_hi(u3));
    }
    for (; e < e1; ++e) {
        uint32_t uu = U[(long)csr_src[e] * 64 + lane];
        s0 += bf_lo(uu); s1 += bf_hi(uu);
    }
    float d = dinv[n];
    float r0 = d * s0, r1 = d * s1;
    if constexpr (BIAS_RELU) {
        r0 = fmaxf(r0 + bias[2 * lane], 0.f);
        r1 = fmaxf(r1 + bias[2 * lane + 1], 0.f);
    }
    Out[(long)n * 64 + lane] = packbf(r0, r1);
}

// ---------------- agg 64 channels + bias/relu + linear head ----------------
__global__ __launch_bounds__(256) void agg64_head(const uint16_t* __restrict__ U,
                                                  const float* __restrict__ dinv,
                                                  const int* __restrict__ row_ptr,
                                                  const int* __restrict__ csr_src,
                                                  const float* __restrict__ b3,
                                                  const float* __restrict__ Wl,
                                                  const float* __restrict__ bl,
                                                  float* __restrict__ out, int N) {
    int wave = threadIdx.x >> 6, lane = threadIdx.x & 63;
    int n = blockIdx.x * 4 + wave;
    if (n >= N) return;
    float s = bf_s(U[(long)n * 64 + lane]);
    int e0 = row_ptr[n], e1 = row_ptr[n + 1];
    int e = e0;
    for (; e + 4 <= e1; e += 4) {
        int i0 = csr_src[e], i1 = csr_src[e + 1], i2 = csr_src[e + 2], i3 = csr_src[e + 3];
        float v0 = bf_s(U[(long)i0 * 64 + lane]);
        float v1 = bf_s(U[(long)i1 * 64 + lane]);
        float v2 = bf_s(U[(long)i2 * 64 + lane]);
        float v3 = bf_s(U[(long)i3 * 64 + lane]);
        s += (v0 + v1) + (v2 + v3);
    }
    for (; e < e1; ++e) s += bf_s(U[(long)csr_src[e] * 64 + lane]);
    float h = fmaxf(dinv[n] * s + b3[lane], 0.f);
    float v = h * Wl[lane];
#pragma unroll
    for (int off = 32; off; off >>= 1) v += __shfl_xor(v, off);
    if (lane == 0) out[n] = v + bl[0];
}

// ---------------- MFMA GEMM: Y[N,M](bf16) = A[N,K](bf16) @ W[K,M](fp32->bf16) ----------------
// Block: 256 thr / 4 waves; wave w owns rows [blk*128 + 32w, +32), all M cols.
// A fragments for the whole K loaded to registers upfront (global, 16B/lane).
// W staged to LDS transposed (wl[m][k], row stride KC+8 shorts -> uniform banks),
// in K-chunks of KC to stay under 64KB static LDS.
// mfma_f32_32x32x16_bf16: A lane(row=l&31, k=8*(l>>5)+0..7); B lane(col=l&31, same k);
// C/D lane: col=l&31, row=(reg&3)+8*(reg>>2)+4*(l>>5).
template <int K, int M, int KC, bool BIAS_RELU, bool SCALE_OUT>
__global__ __launch_bounds__(256, 1) void gemm_mfma(const uint16_t* __restrict__ A,
                                                    const float* __restrict__ W,
                                                    const float* __restrict__ bias,
                                                    const float* __restrict__ dinv,
                                                    uint16_t* __restrict__ Y, int N) {
    constexpr int NT = M / 32;     // col tiles per wave
    constexpr int NK = K / 16;     // k steps total
    constexpr int SD = KC + 8;     // LDS row stride (shorts), 16B-aligned rows
    __shared__ short wl[M * SD];

    int t = threadIdx.x;
    int wave = t >> 6, lane = t & 63;
    int l31 = lane & 31, lhi = lane >> 5;
    long row0 = (long)blockIdx.x * 128 + wave * 32;

    // all A fragments upfront (clamped rows for the tail block; stores are guarded)
    bf16x8 afrag[NK];
    {
        long arow = row0 + l31; if (arow > N - 1) arow = N - 1;
        const uint16_t* ap = A + arow * K + lhi * 8;
#pragma unroll
        for (int s = 0; s < NK; ++s)
            afrag[s] = *(const bf16x8*)(ap + s * 16);
    }

    f32x16 acc[NT];
#pragma unroll
    for (int c = 0; c < NT; ++c)
#pragma unroll
        for (int r = 0; r < 16; ++r) acc[c][r] = 0.f;

    for (int kc0 = 0; kc0 < K; kc0 += KC) {
        for (int idx = t; idx < KC * M; idx += 256) {
            int k = idx / M, m = idx % M;          // consecutive t -> consecutive m (coalesced)
            wl[m * SD + k] = (short)f2bf(W[(long)(kc0 + k) * M + m]);
        }
        __syncthreads();
#pragma unroll
        for (int s = 0; s < KC / 16; ++s) {
            const short* bp = &wl[l31 * SD + s * 16 + lhi * 8];
#pragma unroll
            for (int c = 0; c < NT; ++c) {
                bf16x8 bfrag = *(const bf16x8*)(bp + c * 32 * SD);
                acc[c] = __builtin_amdgcn_mfma_f32_32x32x16_bf16(
                    afrag[kc0 / 16 + s], bfrag, acc[c], 0, 0, 0);
            }
        }
        __syncthreads();
    }

#pragma unroll
    for (int c = 0; c < NT; ++c) {
        int col = c * 32 + l31;
        float bv = BIAS_RELU ? bias[col] : 0.f;
#pragma unroll
        for (int r = 0; r < 16; ++r) {
            long row = row0 + (r & 3) + 8 * (r >> 2) + 4 * lhi;
            if (row < N) {
                float v = acc[c][r];
                if constexpr (BIAS_RELU) v = fmaxf(v + bv, 0.f);
                if constexpr (SCALE_OUT) v *= dinv[row];
                Y[row * M + col] = f2bf(v);
            }
        }
    }
}

extern "C" void kernel_launch(void* const* d_in, const int* in_sizes, int n_in,
                              void* d_out, int out_size, void* d_ws, size_t ws_size,
                              hipStream_t stream) {
    const float* x  = (const float*)d_in[0];
    const int* edge = (const int*)d_in[1];
    const float* W1 = (const float*)d_in[2];
    const float* b1 = (const float*)d_in[3];
    const float* W2 = (const float*)d_in[4];
    const float* b2 = (const float*)d_in[5];
    const float* W3 = (const float*)d_in[6];
    const float* b3 = (const float*)d_in[7];
    const float* Wl = (const float*)d_in[8];
    const float* bl = (const float*)d_in[9];
    float* out = (float*)d_out;

    int N = in_sizes[0] / 128;   // 100000
    int E = in_sizes[1] / 2;     // 800000
    const int* src = edge;
    const int* dst = edge + E;

    char* ws = (char*)d_ws;
    size_t off = 0;
    auto alloc = [&](size_t bytes) {
        void* p = ws + off;
        off += (bytes + 255) & ~(size_t)255;
        return p;
    };
    int*      cnt     = (int*)     alloc((size_t)N * 4);
    int*      row_ptr = (int*)     alloc((size_t)(N + 1) * 4);
    float*    dinv    = (float*)   alloc((size_t)N * 4);
    int*      csr_src = (int*)     alloc((size_t)E * 4);
    uint32_t* B_a     = (uint32_t*)alloc((size_t)N * 64 * 4);    // 128ch bf16
    uint32_t* B_b     = (uint32_t*)alloc((size_t)N * 64 * 4);    // 128ch bf16
    uint32_t* B_c     = (uint32_t*)alloc((size_t)N * 128 * 4);   // 256ch bf16
    (void)ws_size; (void)n_in; (void)out_size;

    // graph preprocessing (rebuilt every launch; ws is re-poisoned)
    hipMemsetAsync(cnt, 0, (size_t)N * 4, stream);
    hist_kernel<<<(E + 255) / 256, 256, 0, stream>>>(dst, cnt, E);
    dinv_kernel<<<(N + 255) / 256, 256, 0, stream>>>(cnt, dinv, N);
    scan_kernel<<<1, 1024, 0, stream>>>(cnt, row_ptr, N);
    fill_kernel<<<(E + 255) / 256, 256, 0, stream>>>(src, dst, row_ptr, cnt, csr_src, E);

    // P0
    scale_cvt<<<(int)(((long)N * 64 + 255) / 256), 256, 0, stream>>>(x, dinv, B_a, (long)N * 64);
    // layer 1
    agg128<false><<<(N + 3) / 4, 256, 0, stream>>>(B_a, dinv, row_ptr, csr_src, nullptr, B_b, N);
    gemm_mfma<128, 256, 64, true, false><<<(N + 127) / 128, 256, 0, stream>>>(
        (const uint16_t*)B_b, W1, b1, nullptr, (uint16_t*)B_c, N);
    // layer 2
    gemm_mfma<256, 128, 128, false, true><<<(N + 127) / 128, 256, 0, stream>>>(
        (const uint16_t*)B_c, W2, nullptr, dinv, (uint16_t*)B_a, N);
    agg128<true><<<(N + 3) / 4, 256, 0, stream>>>(B_a, dinv, row_ptr, csr_src, b2, B_b, N);
    // layer 3
    gemm_mfma<128, 64, 64, false, true><<<(N + 127) / 128, 256, 0, stream>>>(
        (const uint16_t*)B_b, W3, nullptr, dinv, (uint16_t*)B_a, N);
    // agg + head
    agg64_head<<<(N + 3) / 4, 256, 0, stream>>>(
        (const uint16_t*)B_a, dinv, row_ptr, csr_src, b3, Wl, bl, out, N);
}

// Round 4
// 435.308 us; speedup vs baseline: 2.2996x; 1.3914x over previous
//
#include <hip/hip_runtime.h>
#include <hip/hip_bf16.h>
#include <stdint.h>

// GCN 3-layer + head, bf16 data path, fp32 accumulate everywhere.
// Identity: Â(XW) = (ÂX)W; aggregate on the narrower side.
// Scaled-space trick: store ṽ = dinv⊙v (bf16) so the gather loop is a pure
// row-sum (no per-edge dinv), with dinv scaling folded into producer/consumer.
// Pipeline:
//   P0:  U0 = bf16(d ⊙ x)                                  [B_a]
//   agg1: A1 = bf16(d_i*(U0_i + ΣU0_s))                    [B_b]
//   G1:  H1 = bf16(relu(A1@W1 + b1))                       [B_c]
//   G2:  U2 = bf16(d ⊙ (H1@W2))                            [B_a]
//   agg2: H2 = bf16(relu(d_i*(U2_i + ΣU2_s) + b2))         [B_b]
//   G3:  U3 = bf16(d ⊙ (H2@W3))                            [B_a]
//   agg3+head: h3 = relu(d_i*(U3_i+ΣU3_s)+b3); out = h3·Wl + bl

typedef __attribute__((ext_vector_type(8))) short bf16x8;
typedef __attribute__((ext_vector_type(16))) float f32x16;

__device__ __forceinline__ float bf_lo(uint32_t u) {
    union { uint32_t i; float f; } v; v.i = u << 16; return v.f;
}
__device__ __forceinline__ float bf_hi(uint32_t u) {
    union { uint32_t i; float f; } v; v.i = u & 0xffff0000u; return v.f;
}
__device__ __forceinline__ float bf_s(uint16_t h) {
    union { uint32_t i; float f; } v; v.i = ((uint32_t)h) << 16; return v.f;
}
__device__ __forceinline__ uint16_t f2bf(float f) {   // RNE
    union { float f; uint32_t i; } v; v.f = f;
    uint32_t r = v.i + 0x7fffu + ((v.i >> 16) & 1u);
    return (uint16_t)(r >> 16);
}
__device__ __forceinline__ uint32_t packbf(float a, float b) {
    return (uint32_t)f2bf(a) | ((uint32_t)f2bf(b) << 16);
}

// ---------------- graph preprocessing ----------------
__global__ __launch_bounds__(256) void hist_kernel(const int* __restrict__ dst,
                                                   int* __restrict__ cnt, int E) {
    int e = blockIdx.x * 256 + threadIdx.x;
    if (e < E) atomicAdd(&cnt[dst[e]], 1);
}

__global__ __launch_bounds__(256) void dinv_kernel(const int* __restrict__ cnt,
                                                   float* __restrict__ dinv, int N) {
    int i = blockIdx.x * 256 + threadIdx.x;
    if (i < N) dinv[i] = rsqrtf((float)cnt[i] + 1.0f);
}

// 3-phase scan (N up to 128*1024 elements; here N=100000 -> 98 blocks).
// Phase 1: per-block (1024 elems, 256 thr x4) local EXCLUSIVE scan -> row_ptr,
//          block total -> bsum[b].
__global__ __launch_bounds__(256) void scan_blk(const int* __restrict__ cnt,
                                                int* __restrict__ row_ptr,
                                                int* __restrict__ bsum, int N) {
    int b = blockIdx.x, t = threadIdx.x;
    int base = b * 1024 + t * 4;
    int v0 = 0, v1 = 0, v2 = 0, v3 = 0;
    if (base + 3 < N) {
        int4 q = *(const int4*)(cnt + base);
        v0 = q.x; v1 = q.y; v2 = q.z; v3 = q.w;
    } else if (base < N) {
        v0 = cnt[base];
        if (base + 1 < N) v1 = cnt[base + 1];
        if (base + 2 < N) v2 = cnt[base + 2];
    }
    int tsum = v0 + v1 + v2 + v3;
    __shared__ int ps[256];
    ps[t] = tsum;
    __syncthreads();
    for (int off = 1; off < 256; off <<= 1) {
        int x = (t >= off) ? ps[t - off] : 0;
        __syncthreads();
        ps[t] += x;
        __syncthreads();
    }
    int ex = (t == 0) ? 0 : ps[t - 1];
    if (t == 255) bsum[b] = ps[255];
    if (base + 3 < N) {
        int4 w; w.x = ex; w.y = ex + v0; w.z = ex + v0 + v1; w.w = ex + v0 + v1 + v2;
        *(int4*)(row_ptr + base) = w;
    } else if (base < N) {
        row_ptr[base] = ex;
        if (base + 1 < N) row_ptr[base + 1] = ex + v0;
        if (base + 2 < N) row_ptr[base + 2] = ex + v0 + v1;
    }
}

// Phase 2: one block exclusive-scans the <=128 block sums in place.
__global__ __launch_bounds__(128) void scan_tops(int* __restrict__ bsum, int NB) {
    __shared__ int ps[128];
    int t = threadIdx.x;
    int v = (t < NB) ? bsum[t] : 0;
    ps[t] = v;
    __syncthreads();
    for (int off = 1; off < 128; off <<= 1) {
        int x = (t >= off) ? ps[t - off] : 0;
        __syncthreads();
        ps[t] += x;
        __syncthreads();
    }
    if (t < NB) bsum[t] = (t == 0) ? 0 : ps[t - 1];
}

// Phase 3: add block offsets; row_ptr[N] = E analytically.
__global__ __launch_bounds__(256) void scan_add(int* __restrict__ row_ptr,
                                                const int* __restrict__ bsum,
                                                int N, int E) {
    int b = blockIdx.x, t = threadIdx.x;
    int base = b * 1024 + t * 4;
    int off = bsum[b];
    if (base + 3 < N) {
        int4 q = *(int4*)(row_ptr + base);
        q.x += off; q.y += off; q.z += off; q.w += off;
        *(int4*)(row_ptr + base) = q;
    } else {
        for (int i = 0; i < 4; ++i)
            if (base + i < N) row_ptr[base + i] += off;
    }
    if (b == 0 && t == 0) row_ptr[N] = E;
}

__global__ __launch_bounds__(256) void fill_kernel(const int* __restrict__ src,
                                                   const int* __restrict__ dst,
                                                   const int* __restrict__ row_ptr,
                                                   int* __restrict__ cnt,
                                                   int* __restrict__ csr_src, int E) {
    int e = blockIdx.x * 256 + threadIdx.x;
    if (e < E) {
        int d = dst[e];
        int old = atomicSub(&cnt[d], 1);
        csr_src[row_ptr[d + 1] - old] = src[e];
    }
}

// ---------------- P0: U0 = bf16(dinv ⊙ x) ----------------
__global__ __launch_bounds__(256) void scale_cvt(const float* __restrict__ x,
                                                 const float* __restrict__ dinv,
                                                 uint32_t* __restrict__ U, long total) {
    long i = (long)blockIdx.x * 256 + threadIdx.x;
    if (i >= total) return;
    int row = (int)(i >> 6);
    float2 v = ((const float2*)x)[i];
    float d = dinv[row];
    U[i] = packbf(d * v.x, d * v.y);
}

// ---------------- aggregation, 128 channels (wave per node, bf16x2/lane) ----------------
// 8 gathers always in flight; tail handled by clamped index + 0/1-mask FMA
// (e-range is wave-uniform, so masks are uniform; clamped loads are L0 hits).
template <bool BIAS_RELU>
__global__ __launch_bounds__(256) void agg128(const uint32_t* __restrict__ U,
                                              const float* __restrict__ dinv,
                                              const int* __restrict__ row_ptr,
                                              const int* __restrict__ csr_src,
                                              const float* __restrict__ bias,
                                              uint32_t* __restrict__ Out, int N) {
    int wave = threadIdx.x >> 6, lane = threadIdx.x & 63;
    int n = blockIdx.x * 4 + wave;
    if (n >= N) return;
    uint32_t u = U[(long)n * 64 + lane];
    float s0 = bf_lo(u), s1 = bf_hi(u);
    int e0 = row_ptr[n], e1 = row_ptr[n + 1];
    for (int e = e0; e < e1; e += 8) {
        int idx[8];
        uint32_t uu[8];
#pragma unroll
        for (int j = 0; j < 8; ++j) {
            int ee = e + j; if (ee > e1 - 1) ee = e1 - 1;
            idx[j] = csr_src[ee];
        }
#pragma unroll
        for (int j = 0; j < 8; ++j) uu[j] = U[(long)idx[j] * 64 + lane];
#pragma unroll
        for (int j = 0; j < 8; ++j) {
            float m = (e + j < e1) ? 1.f : 0.f;
            s0 += m * bf_lo(uu[j]);
            s1 += m * bf_hi(uu[j]);
        }
    }
    float d = dinv[n];
    float r0 = d * s0, r1 = d * s1;
    if constexpr (BIAS_RELU) {
        r0 = fmaxf(r0 + bias[2 * lane], 0.f);
        r1 = fmaxf(r1 + bias[2 * lane + 1], 0.f);
    }
    Out[(long)n * 64 + lane] = packbf(r0, r1);
}

// ---------------- agg 64 channels + bias/relu + linear head ----------------
__global__ __launch_bounds__(256) void agg64_head(const uint16_t* __restrict__ U,
                                                  const float* __restrict__ dinv,
                                                  const int* __restrict__ row_ptr,
                                                  const int* __restrict__ csr_src,
                                                  const float* __restrict__ b3,
                                                  const float* __restrict__ Wl,
                                                  const float* __restrict__ bl,
                                                  float* __restrict__ out, int N) {
    int wave = threadIdx.x >> 6, lane = threadIdx.x & 63;
    int n = blockIdx.x * 4 + wave;
    if (n >= N) return;
    float s = bf_s(U[(long)n * 64 + lane]);
    int e0 = row_ptr[n], e1 = row_ptr[n + 1];
    for (int e = e0; e < e1; e += 8) {
        int idx[8];
        uint16_t uu[8];
#pragma unroll
        for (int j = 0; j < 8; ++j) {
            int ee = e + j; if (ee > e1 - 1) ee = e1 - 1;
            idx[j] = csr_src[ee];
        }
#pragma unroll
        for (int j = 0; j < 8; ++j) uu[j] = U[(long)idx[j] * 64 + lane];
#pragma unroll
        for (int j = 0; j < 8; ++j) {
            float m = (e + j < e1) ? 1.f : 0.f;
            s += m * bf_s(uu[j]);
        }
    }
    float h = fmaxf(dinv[n] * s + b3[lane], 0.f);
    float v = h * Wl[lane];
#pragma unroll
    for (int off = 32; off; off >>= 1) v += __shfl_xor(v, off);
    if (lane == 0) out[n] = v + bl[0];
}

// ---------------- MFMA GEMM: Y[N,M](bf16) = A[N,K](bf16) @ W[K,M](fp32->bf16) ----------------
// Block: 256 thr / 4 waves; wave w owns rows [blk*128 + 32w, +32), all M cols.
// A fragments for the whole K loaded to registers upfront (global, 16B/lane).
// W staged to LDS transposed (wl[m][k], row stride KC+8 shorts), K-chunks of KC.
// mfma_f32_32x32x16_bf16: A lane(row=l&31, k=8*(l>>5)+0..7); B lane(col=l&31, same k);
// C/D lane: col=l&31, row=(reg&3)+8*(reg>>2)+4*(l>>5).
template <int K, int M, int KC, bool BIAS_RELU, bool SCALE_OUT>
__global__ __launch_bounds__(256, 1) void gemm_mfma(const uint16_t* __restrict__ A,
                                                    const float* __restrict__ W,
                                                    const float* __restrict__ bias,
                                                    const float* __restrict__ dinv,
                                                    uint16_t* __restrict__ Y, int N) {
    constexpr int NT = M / 32;
    constexpr int NK = K / 16;
    constexpr int SD = KC + 8;
    __shared__ short wl[M * SD];

    int t = threadIdx.x;
    int wave = t >> 6, lane = t & 63;
    int l31 = lane & 31, lhi = lane >> 5;
    long row0 = (long)blockIdx.x * 128 + wave * 32;

    bf16x8 afrag[NK];
    {
        long arow = row0 + l31; if (arow > N - 1) arow = N - 1;
        const uint16_t* ap = A + arow * K + lhi * 8;
#pragma unroll
        for (int s = 0; s < NK; ++s)
            afrag[s] = *(const bf16x8*)(ap + s * 16);
    }

    f32x16 acc[NT];
#pragma unroll
    for (int c = 0; c < NT; ++c)
#pragma unroll
        for (int r = 0; r < 16; ++r) acc[c][r] = 0.f;

    for (int kc0 = 0; kc0 < K; kc0 += KC) {
        for (int idx = t; idx < KC * M; idx += 256) {
            int k = idx / M, m = idx % M;          // consecutive t -> consecutive m (coalesced)
            wl[m * SD + k] = (short)f2bf(W[(long)(kc0 + k) * M + m]);
        }
        __syncthreads();
#pragma unroll
        for (int s = 0; s < KC / 16; ++s) {
            const short* bp = &wl[l31 * SD + s * 16 + lhi * 8];
#pragma unroll
            for (int c = 0; c < NT; ++c) {
                bf16x8 bfrag = *(const bf16x8*)(bp + c * 32 * SD);
                acc[c] = __builtin_amdgcn_mfma_f32_32x32x16_bf16(
                    afrag[kc0 / 16 + s], bfrag, acc[c], 0, 0, 0);
            }
        }
        __syncthreads();
    }

#pragma unroll
    for (int c = 0; c < NT; ++c) {
        int col = c * 32 + l31;
        float bv = BIAS_RELU ? bias[col] : 0.f;
#pragma unroll
        for (int r = 0; r < 16; ++r) {
            long row = row0 + (r & 3) + 8 * (r >> 2) + 4 * lhi;
            if (row < N) {
                float v = acc[c][r];
                if constexpr (BIAS_RELU) v = fmaxf(v + bv, 0.f);
                if constexpr (SCALE_OUT) v *= dinv[row];
                Y[row * M + col] = f2bf(v);
            }
        }
    }
}

extern "C" void kernel_launch(void* const* d_in, const int* in_sizes, int n_in,
                              void* d_out, int out_size, void* d_ws, size_t ws_size,
                              hipStream_t stream) {
    const float* x  = (const float*)d_in[0];
    const int* edge = (const int*)d_in[1];
    const float* W1 = (const float*)d_in[2];
    const float* b1 = (const float*)d_in[3];
    const float* W2 = (const float*)d_in[4];
    const float* b2 = (const float*)d_in[5];
    const float* W3 = (const float*)d_in[6];
    const float* b3 = (const float*)d_in[7];
    const float* Wl = (const float*)d_in[8];
    const float* bl = (const float*)d_in[9];
    float* out = (float*)d_out;

    int N = in_sizes[0] / 128;   // 100000
    int E = in_sizes[1] / 2;     // 800000
    const int* src = edge;
    const int* dst = edge + E;

    char* ws = (char*)d_ws;
    size_t off = 0;
    auto alloc = [&](size_t bytes) {
        void* p = ws + off;
        off += (bytes + 255) & ~(size_t)255;
        return p;
    };
    int*      cnt     = (int*)     alloc((size_t)N * 4);
    int*      row_ptr = (int*)     alloc((size_t)(N + 1) * 4);
    float*    dinv    = (float*)   alloc((size_t)N * 4);
    int*      csr_src = (int*)     alloc((size_t)E * 4);
    int*      bsum    = (int*)     alloc(128 * 4);
    uint32_t* B_a     = (uint32_t*)alloc((size_t)N * 64 * 4);    // 128ch bf16
    uint32_t* B_b     = (uint32_t*)alloc((size_t)N * 64 * 4);    // 128ch bf16
    uint32_t* B_c     = (uint32_t*)alloc((size_t)N * 128 * 4);   // 256ch bf16
    (void)ws_size; (void)n_in; (void)out_size;

    int NB = (N + 1023) / 1024;   // 98 <= 128 (scan_tops capacity)

    // graph preprocessing (rebuilt every launch; ws is re-poisoned)
    hipMemsetAsync(cnt, 0, (size_t)N * 4, stream);
    hist_kernel<<<(E + 255) / 256, 256, 0, stream>>>(dst, cnt, E);
    dinv_kernel<<<(N + 255) / 256, 256, 0, stream>>>(cnt, dinv, N);
    scan_blk<<<NB, 256, 0, stream>>>(cnt, row_ptr, bsum, N);
    scan_tops<<<1, 128, 0, stream>>>(bsum, NB);
    scan_add<<<NB, 256, 0, stream>>>(row_ptr, bsum, N, E);
    fill_kernel<<<(E + 255) / 256, 256, 0, stream>>>(src, dst, row_ptr, cnt, csr_src, E);

    // P0
    scale_cvt<<<(int)(((long)N * 64 + 255) / 256), 256, 0, stream>>>(x, dinv, B_a, (long)N * 64);
    // layer 1
    agg128<false><<<(N + 3) / 4, 256, 0, stream>>>(B_a, dinv, row_ptr, csr_src, nullptr, B_b, N);
    gemm_mfma<128, 256, 64, true, false><<<(N + 127) / 128, 256, 0, stream>>>(
        (const uint16_t*)B_b, W1, b1, nullptr, (uint16_t*)B_c, N);
    // layer 2
    gemm_mfma<256, 128, 128, false, true><<<(N + 127) / 128, 256, 0, stream>>>(
        (const uint16_t*)B_c, W2, nullptr, dinv, (uint16_t*)B_a, N);
    agg128<true><<<(N + 3) / 4, 256, 0, stream>>>(B_a, dinv, row_ptr, csr_src, b2, B_b, N);
    // layer 3
    gemm_mfma<128, 64, 64, false, true><<<(N + 127) / 128, 256, 0, stream>>>(
        (const uint16_t*)B_b, W3, nullptr, dinv, (uint16_t*)B_a, N);
    // agg + head
    agg64_head<<<(N + 3) / 4, 256, 0, stream>>>(
        (const uint16_t*)B_a, dinv, row_ptr, csr_src, b3, Wl, bl, out, N);
}

// Round 5
// 413.623 us; speedup vs baseline: 2.4202x; 1.0524x over previous
//
#include <hip/hip_runtime.h>
#include <hip/hip_bf16.h>
#include <stdint.h>

// GCN 3-layer + head, bf16 data path, fp32 accumulate everywhere.
// Identity: Â(XW) = (ÂX)W; aggregate on the narrower side.
// Scaled-space trick: store ṽ = dinv⊙v (bf16) so the gather loop is a pure
// row-sum; dinv scaling folded into producer/consumer epilogues.
// This round: W pre-converted/transposed to bf16 ONCE (wprep), so GEMM
// LDS staging is a pure 16B-vector copy (was: per-element div/mod + f2bf).

typedef __attribute__((ext_vector_type(8))) short bf16x8;
typedef __attribute__((ext_vector_type(16))) float f32x16;

__device__ __forceinline__ float bf_lo(uint32_t u) {
    union { uint32_t i; float f; } v; v.i = u << 16; return v.f;
}
__device__ __forceinline__ float bf_hi(uint32_t u) {
    union { uint32_t i; float f; } v; v.i = u & 0xffff0000u; return v.f;
}
__device__ __forceinline__ float bf_s(uint16_t h) {
    union { uint32_t i; float f; } v; v.i = ((uint32_t)h) << 16; return v.f;
}
__device__ __forceinline__ uint16_t f2bf(float f) {   // RNE
    union { float f; uint32_t i; } v; v.f = f;
    uint32_t r = v.i + 0x7fffu + ((v.i >> 16) & 1u);
    return (uint16_t)(r >> 16);
}
__device__ __forceinline__ uint32_t packbf(float a, float b) {
    return (uint32_t)f2bf(a) | ((uint32_t)f2bf(b) << 16);
}

// ---------------- graph preprocessing ----------------
__global__ __launch_bounds__(256) void hist_kernel(const int* __restrict__ dst,
                                                   int* __restrict__ cnt, int E) {
    int e = blockIdx.x * 256 + threadIdx.x;
    if (e < E) atomicAdd(&cnt[dst[e]], 1);
}

__global__ __launch_bounds__(256) void dinv_kernel(const int* __restrict__ cnt,
                                                   float* __restrict__ dinv, int N) {
    int i = blockIdx.x * 256 + threadIdx.x;
    if (i < N) dinv[i] = rsqrtf((float)cnt[i] + 1.0f);
}

// 3-phase scan (98 blocks of 1024 elems).
__global__ __launch_bounds__(256) void scan_blk(const int* __restrict__ cnt,
                                                int* __restrict__ row_ptr,
                                                int* __restrict__ bsum, int N) {
    int b = blockIdx.x, t = threadIdx.x;
    int base = b * 1024 + t * 4;
    int v0 = 0, v1 = 0, v2 = 0, v3 = 0;
    if (base + 3 < N) {
        int4 q = *(const int4*)(cnt + base);
        v0 = q.x; v1 = q.y; v2 = q.z; v3 = q.w;
    } else if (base < N) {
        v0 = cnt[base];
        if (base + 1 < N) v1 = cnt[base + 1];
        if (base + 2 < N) v2 = cnt[base + 2];
    }
    int tsum = v0 + v1 + v2 + v3;
    __shared__ int ps[256];
    ps[t] = tsum;
    __syncthreads();
    for (int off = 1; off < 256; off <<= 1) {
        int x = (t >= off) ? ps[t - off] : 0;
        __syncthreads();
        ps[t] += x;
        __syncthreads();
    }
    int ex = (t == 0) ? 0 : ps[t - 1];
    if (t == 255) bsum[b] = ps[255];
    if (base + 3 < N) {
        int4 w; w.x = ex; w.y = ex + v0; w.z = ex + v0 + v1; w.w = ex + v0 + v1 + v2;
        *(int4*)(row_ptr + base) = w;
    } else if (base < N) {
        row_ptr[base] = ex;
        if (base + 1 < N) row_ptr[base + 1] = ex + v0;
        if (base + 2 < N) row_ptr[base + 2] = ex + v0 + v1;
    }
}

__global__ __launch_bounds__(128) void scan_tops(int* __restrict__ bsum, int NB) {
    __shared__ int ps[128];
    int t = threadIdx.x;
    int v = (t < NB) ? bsum[t] : 0;
    ps[t] = v;
    __syncthreads();
    for (int off = 1; off < 128; off <<= 1) {
        int x = (t >= off) ? ps[t - off] : 0;
        __syncthreads();
        ps[t] += x;
        __syncthreads();
    }
    if (t < NB) bsum[t] = (t == 0) ? 0 : ps[t - 1];
}

__global__ __launch_bounds__(256) void scan_add(int* __restrict__ row_ptr,
                                                const int* __restrict__ bsum,
                                                int N, int E) {
    int b = blockIdx.x, t = threadIdx.x;
    int base = b * 1024 + t * 4;
    int off = bsum[b];
    if (base + 3 < N) {
        int4 q = *(int4*)(row_ptr + base);
        q.x += off; q.y += off; q.z += off; q.w += off;
        *(int4*)(row_ptr + base) = q;
    } else {
        for (int i = 0; i < 4; ++i)
            if (base + i < N) row_ptr[base + i] += off;
    }
    if (b == 0 && t == 0) row_ptr[N] = E;
}

__global__ __launch_bounds__(256) void fill_kernel(const int* __restrict__ src,
                                                   const int* __restrict__ dst,
                                                   const int* __restrict__ row_ptr,
                                                   int* __restrict__ cnt,
                                                   int* __restrict__ csr_src, int E) {
    int e = blockIdx.x * 256 + threadIdx.x;
    if (e < E) {
        int d = dst[e];
        int old = atomicSub(&cnt[d], 1);
        csr_src[row_ptr[d + 1] - old] = src[e];
    }
}

// ---------------- wprep: W (fp32, [k][m]) -> Wt (bf16, [m][k]) for all 3 ----------------
// Write-coalesced: thread j writes Wt[j]; j -> (m = j/K, k = j%K); read W[k*M + m].
template <int K, int M>
__device__ __forceinline__ void wprep_one(const float* __restrict__ W,
                                          uint16_t* __restrict__ Wt, int j) {
    int m = j / K, k = j % K;
    Wt[j] = f2bf(W[k * M + m]);
}
__global__ __launch_bounds__(256) void wprep(const float* __restrict__ W1,
                                             const float* __restrict__ W2,
                                             const float* __restrict__ W3,
                                             uint16_t* __restrict__ Wt1,
                                             uint16_t* __restrict__ Wt2,
                                             uint16_t* __restrict__ Wt3) {
    int i = blockIdx.x * 256 + threadIdx.x;
    if (i < 32768) {
        wprep_one<128, 256>(W1, Wt1, i);          // W1: 128x256
    } else if (i < 65536) {
        wprep_one<256, 128>(W2, Wt2, i - 32768);  // W2: 256x128
    } else if (i < 73728) {
        wprep_one<128, 64>(W3, Wt3, i - 65536);   // W3: 128x64
    }
}

// ---------------- P0: U0 = bf16(dinv ⊙ x) ----------------
__global__ __launch_bounds__(256) void scale_cvt(const float* __restrict__ x,
                                                 const float* __restrict__ dinv,
                                                 uint32_t* __restrict__ U, long total) {
    long i = (long)blockIdx.x * 256 + threadIdx.x;
    if (i >= total) return;
    int row = (int)(i >> 6);
    float2 v = ((const float2*)x)[i];
    float d = dinv[row];
    U[i] = packbf(d * v.x, d * v.y);
}

// ---------------- aggregation, 128 channels (wave per node) ----------------
template <bool BIAS_RELU>
__global__ __launch_bounds__(256) void agg128(const uint32_t* __restrict__ U,
                                              const float* __restrict__ dinv,
                                              const int* __restrict__ row_ptr,
                                              const int* __restrict__ csr_src,
                                              const float* __restrict__ bias,
                                              uint32_t* __restrict__ Out, int N) {
    int wave = threadIdx.x >> 6, lane = threadIdx.x & 63;
    int n = blockIdx.x * 4 + wave;
    if (n >= N) return;
    uint32_t u = U[(long)n * 64 + lane];
    float s0 = bf_lo(u), s1 = bf_hi(u);
    int e0 = row_ptr[n], e1 = row_ptr[n + 1];
    for (int e = e0; e < e1; e += 8) {
        int idx[8];
        uint32_t uu[8];
#pragma unroll
        for (int j = 0; j < 8; ++j) {
            int ee = e + j; if (ee > e1 - 1) ee = e1 - 1;
            idx[j] = csr_src[ee];
        }
#pragma unroll
        for (int j = 0; j < 8; ++j) uu[j] = U[(long)idx[j] * 64 + lane];
#pragma unroll
        for (int j = 0; j < 8; ++j) {
            float m = (e + j < e1) ? 1.f : 0.f;
            s0 += m * bf_lo(uu[j]);
            s1 += m * bf_hi(uu[j]);
        }
    }
    float d = dinv[n];
    float r0 = d * s0, r1 = d * s1;
    if constexpr (BIAS_RELU) {
        r0 = fmaxf(r0 + bias[2 * lane], 0.f);
        r1 = fmaxf(r1 + bias[2 * lane + 1], 0.f);
    }
    Out[(long)n * 64 + lane] = packbf(r0, r1);
}

// ---------------- agg 64 channels + bias/relu + linear head ----------------
__global__ __launch_bounds__(256) void agg64_head(const uint16_t* __restrict__ U,
                                                  const float* __restrict__ dinv,
                                                  const int* __restrict__ row_ptr,
                                                  const int* __restrict__ csr_src,
                                                  const float* __restrict__ b3,
                                                  const float* __restrict__ Wl,
                                                  const float* __restrict__ bl,
                                                  float* __restrict__ out, int N) {
    int wave = threadIdx.x >> 6, lane = threadIdx.x & 63;
    int n = blockIdx.x * 4 + wave;
    if (n >= N) return;
    float s = bf_s(U[(long)n * 64 + lane]);
    int e0 = row_ptr[n], e1 = row_ptr[n + 1];
    for (int e = e0; e < e1; e += 8) {
        int idx[8];
        uint16_t uu[8];
#pragma unroll
        for (int j = 0; j < 8; ++j) {
            int ee = e + j; if (ee > e1 - 1) ee = e1 - 1;
            idx[j] = csr_src[ee];
        }
#pragma unroll
        for (int j = 0; j < 8; ++j) uu[j] = U[(long)idx[j] * 64 + lane];
#pragma unroll
        for (int j = 0; j < 8; ++j) {
            float m = (e + j < e1) ? 1.f : 0.f;
            s += m * bf_s(uu[j]);
        }
    }
    float h = fmaxf(dinv[n] * s + b3[lane], 0.f);
    float v = h * Wl[lane];
#pragma unroll
    for (int off = 32; off; off >>= 1) v += __shfl_xor(v, off);
    if (lane == 0) out[n] = v + bl[0];
}

// ---------------- MFMA GEMM: Y[N,M](bf16) = A[N,K](bf16) @ Wt[M,K](bf16) ----------------
// Wt is pre-transposed bf16 [m][k]. Staging = pure 16B vector copy into LDS
// rows of stride SD=KC+8 shorts (36 dwords ≡ 4 mod 32 -> quarter-wave b128
// reads are bank-conflict-free; measured 0 conflicts in R3/R4).
// Block: 256 thr / 4 waves; wave w owns rows [blk*128+32w, +32), all M cols.
// mfma_f32_32x32x16_bf16: A lane(row=l&31, k=8*(l>>5)+j); B lane(col=l&31, same k);
// C/D lane: col=l&31, row=(reg&3)+8*(reg>>2)+4*(l>>5).
template <int K, int M, bool BIAS_RELU, bool SCALE_OUT>
__global__ __launch_bounds__(256, 2) void gemm_mfma(const uint16_t* __restrict__ A,
                                                    const uint16_t* __restrict__ Wt,
                                                    const float* __restrict__ bias,
                                                    const float* __restrict__ dinv,
                                                    uint16_t* __restrict__ Y, int N) {
    constexpr int NT = M / 32;      // col tiles per wave
    constexpr int NK = K / 16;      // k-steps total
    constexpr int KC = 64;          // K-chunk in LDS
    constexpr int SD = KC + 8;      // LDS row stride (shorts)
    constexpr int CPR = KC / 8;     // 16B chunks per LDS row (=8)
    __shared__ short wl[M * SD];

    int t = threadIdx.x;
    int wave = t >> 6, lane = t & 63;
    int l31 = lane & 31, lhi = lane >> 5;
    long row0 = (long)blockIdx.x * 128 + wave * 32;

    // A fragments for the whole K, loaded upfront (latency overlaps staging)
    bf16x8 afrag[NK];
    {
        long arow = row0 + l31; if (arow > N - 1) arow = N - 1;
        const uint16_t* ap = A + arow * K + lhi * 8;
#pragma unroll
        for (int s = 0; s < NK; ++s)
            afrag[s] = *(const bf16x8*)(ap + s * 16);
    }

    f32x16 acc[NT];
#pragma unroll
    for (int c = 0; c < NT; ++c)
#pragma unroll
        for (int r = 0; r < 16; ++r) acc[c][r] = 0.f;

    int r0 = t / CPR, cc8 = (t % CPR) * 8;
    for (int kc0 = 0; kc0 < K; kc0 += KC) {
        // stage Wt[:, kc0:kc0+KC] -> wl (16B vector copies)
#pragma unroll
        for (int r = r0; r < M; r += 256 / CPR)
            *(bf16x8*)(wl + r * SD + cc8) = *(const bf16x8*)(Wt + (long)r * K + kc0 + cc8);
        __syncthreads();
#pragma unroll
        for (int s = 0; s < KC / 16; ++s) {
            const short* bp = wl + l31 * SD + s * 16 + lhi * 8;
#pragma unroll
            for (int c = 0; c < NT; ++c) {
                bf16x8 bfrag = *(const bf16x8*)(bp + c * 32 * SD);
                acc[c] = __builtin_amdgcn_mfma_f32_32x32x16_bf16(
                    afrag[kc0 / 16 + s], bfrag, acc[c], 0, 0, 0);
            }
        }
        __syncthreads();
    }

#pragma unroll
    for (int c = 0; c < NT; ++c) {
        int col = c * 32 + l31;
        float bv = BIAS_RELU ? bias[col] : 0.f;
#pragma unroll
        for (int r = 0; r < 16; ++r) {
            long row = row0 + (r & 3) + 8 * (r >> 2) + 4 * lhi;
            if (row < N) {
                float v = acc[c][r];
                if constexpr (BIAS_RELU) v = fmaxf(v + bv, 0.f);
                if constexpr (SCALE_OUT) v *= dinv[row];
                Y[row * M + col] = f2bf(v);
            }
        }
    }
}

extern "C" void kernel_launch(void* const* d_in, const int* in_sizes, int n_in,
                              void* d_out, int out_size, void* d_ws, size_t ws_size,
                              hipStream_t stream) {
    const float* x  = (const float*)d_in[0];
    const int* edge = (const int*)d_in[1];
    const float* W1 = (const float*)d_in[2];
    const float* b1 = (const float*)d_in[3];
    const float* W2 = (const float*)d_in[4];
    const float* b2 = (const float*)d_in[5];
    const float* W3 = (const float*)d_in[6];
    const float* b3 = (const float*)d_in[7];
    const float* Wl = (const float*)d_in[8];
    const float* bl = (const float*)d_in[9];
    float* out = (float*)d_out;

    int N = in_sizes[0] / 128;   // 100000
    int E = in_sizes[1] / 2;     // 800000
    const int* src = edge;
    const int* dst = edge + E;

    char* ws = (char*)d_ws;
    size_t off = 0;
    auto alloc = [&](size_t bytes) {
        void* p = ws + off;
        off += (bytes + 255) & ~(size_t)255;
        return p;
    };
    int*      cnt     = (int*)     alloc((size_t)N * 4);
    int*      row_ptr = (int*)     alloc((size_t)(N + 1) * 4);
    float*    dinv    = (float*)   alloc((size_t)N * 4);
    int*      csr_src = (int*)     alloc((size_t)E * 4);
    int*      bsum    = (int*)     alloc(128 * 4);
    uint16_t* Wt1     = (uint16_t*)alloc(256 * 128 * 2);
    uint16_t* Wt2     = (uint16_t*)alloc(128 * 256 * 2);
    uint16_t* Wt3     = (uint16_t*)alloc(64 * 128 * 2);
    uint32_t* B_a     = (uint32_t*)alloc((size_t)N * 64 * 4);    // 128ch bf16
    uint32_t* B_b     = (uint32_t*)alloc((size_t)N * 64 * 4);    // 128ch bf16
    uint32_t* B_c     = (uint32_t*)alloc((size_t)N * 128 * 4);   // 256ch bf16
    (void)ws_size; (void)n_in; (void)out_size;

    int NB = (N + 1023) / 1024;   // 98

    // graph preprocessing (rebuilt every launch; ws is re-poisoned)
    hipMemsetAsync(cnt, 0, (size_t)N * 4, stream);
    hist_kernel<<<(E + 255) / 256, 256, 0, stream>>>(dst, cnt, E);
    dinv_kernel<<<(N + 255) / 256, 256, 0, stream>>>(cnt, dinv, N);
    scan_blk<<<NB, 256, 0, stream>>>(cnt, row_ptr, bsum, N);
    scan_tops<<<1, 128, 0, stream>>>(bsum, NB);
    scan_add<<<NB, 256, 0, stream>>>(row_ptr, bsum, N, E);
    fill_kernel<<<(E + 255) / 256, 256, 0, stream>>>(src, dst, row_ptr, cnt, csr_src, E);
    wprep<<<288, 256, 0, stream>>>(W1, W2, W3, Wt1, Wt2, Wt3);

    // P0
    scale_cvt<<<(int)(((long)N * 64 + 255) / 256), 256, 0, stream>>>(x, dinv, B_a, (long)N * 64);
    // layer 1
    agg128<false><<<(N + 3) / 4, 256, 0, stream>>>(B_a, dinv, row_ptr, csr_src, nullptr, B_b, N);
    gemm_mfma<128, 256, true, false><<<(N + 127) / 128, 256, 0, stream>>>(
        (const uint16_t*)B_b, Wt1, b1, nullptr, (uint16_t*)B_c, N);
    // layer 2
    gemm_mfma<256, 128, false, true><<<(N + 127) / 128, 256, 0, stream>>>(
        (const uint16_t*)B_c, Wt2, nullptr, dinv, (uint16_t*)B_a, N);
    agg128<true><<<(N + 3) / 4, 256, 0, stream>>>(B_a, dinv, row_ptr, csr_src, b2, B_b, N);
    // layer 3
    gemm_mfma<128, 64, false, true><<<(N + 127) / 128, 256, 0, stream>>>(
        (const uint16_t*)B_b, Wt3, nullptr, dinv, (uint16_t*)B_a, N);
    // agg + head
    agg64_head<<<(N + 3) / 4, 256, 0, stream>>>(
        (const uint16_t*)B_a, dinv, row_ptr, csr_src, b3, Wl, bl, out, N);
}

// Round 6
// 393.054 us; speedup vs baseline: 2.5468x; 1.0523x over previous
//
#include <hip/hip_runtime.h>
#include <hip/hip_bf16.h>
#include <stdint.h>

// GCN 3-layer + head, bf16 data path, fp32 accumulate everywhere.
// Identity: Â(XW) = (ÂX)W; aggregate on the narrower side.
// Scaled-space trick: store ṽ = dinv⊙v (bf16) so the gather loop is a pure
// row-sum; dinv scaling folded into producer/consumer epilogues.
// This round: TRANSPOSED MFMA (D = Wt·X^T by swapping operand fragments —
// A/B fragments share the same lane layout on gfx950). Each lane then owns
// one NODE and contiguous m-runs -> packed 8B epilogue stores with a single
// base pointer, replacing 128 scalar 2B stores/thread.

typedef __attribute__((ext_vector_type(8))) short bf16x8;
typedef __attribute__((ext_vector_type(16))) float f32x16;

__device__ __forceinline__ float bf_lo(uint32_t u) {
    union { uint32_t i; float f; } v; v.i = u << 16; return v.f;
}
__device__ __forceinline__ float bf_hi(uint32_t u) {
    union { uint32_t i; float f; } v; v.i = u & 0xffff0000u; return v.f;
}
__device__ __forceinline__ float bf_s(uint16_t h) {
    union { uint32_t i; float f; } v; v.i = ((uint32_t)h) << 16; return v.f;
}
__device__ __forceinline__ uint16_t f2bf(float f) {   // RNE
    union { float f; uint32_t i; } v; v.f = f;
    uint32_t r = v.i + 0x7fffu + ((v.i >> 16) & 1u);
    return (uint16_t)(r >> 16);
}
__device__ __forceinline__ uint32_t packbf(float a, float b) {
    return (uint32_t)f2bf(a) | ((uint32_t)f2bf(b) << 16);
}

// ---------------- graph preprocessing ----------------
__global__ __launch_bounds__(256) void hist_kernel(const int* __restrict__ dst,
                                                   int* __restrict__ cnt, int E) {
    int e = blockIdx.x * 256 + threadIdx.x;
    if (e < E) atomicAdd(&cnt[dst[e]], 1);
}

__global__ __launch_bounds__(256) void dinv_kernel(const int* __restrict__ cnt,
                                                   float* __restrict__ dinv, int N) {
    int i = blockIdx.x * 256 + threadIdx.x;
    if (i < N) dinv[i] = rsqrtf((float)cnt[i] + 1.0f);
}

// 3-phase scan (98 blocks of 1024 elems).
__global__ __launch_bounds__(256) void scan_blk(const int* __restrict__ cnt,
                                                int* __restrict__ row_ptr,
                                                int* __restrict__ bsum, int N) {
    int b = blockIdx.x, t = threadIdx.x;
    int base = b * 1024 + t * 4;
    int v0 = 0, v1 = 0, v2 = 0, v3 = 0;
    if (base + 3 < N) {
        int4 q = *(const int4*)(cnt + base);
        v0 = q.x; v1 = q.y; v2 = q.z; v3 = q.w;
    } else if (base < N) {
        v0 = cnt[base];
        if (base + 1 < N) v1 = cnt[base + 1];
        if (base + 2 < N) v2 = cnt[base + 2];
    }
    int tsum = v0 + v1 + v2 + v3;
    __shared__ int ps[256];
    ps[t] = tsum;
    __syncthreads();
    for (int off = 1; off < 256; off <<= 1) {
        int x = (t >= off) ? ps[t - off] : 0;
        __syncthreads();
        ps[t] += x;
        __syncthreads();
    }
    int ex = (t == 0) ? 0 : ps[t - 1];
    if (t == 255) bsum[b] = ps[255];
    if (base + 3 < N) {
        int4 w; w.x = ex; w.y = ex + v0; w.z = ex + v0 + v1; w.w = ex + v0 + v1 + v2;
        *(int4*)(row_ptr + base) = w;
    } else if (base < N) {
        row_ptr[base] = ex;
        if (base + 1 < N) row_ptr[base + 1] = ex + v0;
        if (base + 2 < N) row_ptr[base + 2] = ex + v0 + v1;
    }
}

__global__ __launch_bounds__(128) void scan_tops(int* __restrict__ bsum, int NB) {
    __shared__ int ps[128];
    int t = threadIdx.x;
    int v = (t < NB) ? bsum[t] : 0;
    ps[t] = v;
    __syncthreads();
    for (int off = 1; off < 128; off <<= 1) {
        int x = (t >= off) ? ps[t - off] : 0;
        __syncthreads();
        ps[t] += x;
        __syncthreads();
    }
    if (t < NB) bsum[t] = (t == 0) ? 0 : ps[t - 1];
}

__global__ __launch_bounds__(256) void scan_add(int* __restrict__ row_ptr,
                                                const int* __restrict__ bsum,
                                                int N, int E) {
    int b = blockIdx.x, t = threadIdx.x;
    int base = b * 1024 + t * 4;
    int off = bsum[b];
    if (base + 3 < N) {
        int4 q = *(int4*)(row_ptr + base);
        q.x += off; q.y += off; q.z += off; q.w += off;
        *(int4*)(row_ptr + base) = q;
    } else {
        for (int i = 0; i < 4; ++i)
            if (base + i < N) row_ptr[base + i] += off;
    }
    if (b == 0 && t == 0) row_ptr[N] = E;
}

__global__ __launch_bounds__(256) void fill_kernel(const int* __restrict__ src,
                                                   const int* __restrict__ dst,
                                                   const int* __restrict__ row_ptr,
                                                   int* __restrict__ cnt,
                                                   int* __restrict__ csr_src, int E) {
    int e = blockIdx.x * 256 + threadIdx.x;
    if (e < E) {
        int d = dst[e];
        int old = atomicSub(&cnt[d], 1);
        csr_src[row_ptr[d + 1] - old] = src[e];
    }
}

// ---------------- wprep: W (fp32, [k][m]) -> Wt (bf16, [m][k]) ----------------
template <int K, int M>
__device__ __forceinline__ void wprep_one(const float* __restrict__ W,
                                          uint16_t* __restrict__ Wt, int j) {
    int m = j / K, k = j % K;
    Wt[j] = f2bf(W[k * M + m]);
}
__global__ __launch_bounds__(256) void wprep(const float* __restrict__ W1,
                                             const float* __restrict__ W2,
                                             const float* __restrict__ W3,
                                             uint16_t* __restrict__ Wt1,
                                             uint16_t* __restrict__ Wt2,
                                             uint16_t* __restrict__ Wt3) {
    int i = blockIdx.x * 256 + threadIdx.x;
    if (i < 32768) {
        wprep_one<128, 256>(W1, Wt1, i);          // W1: 128x256
    } else if (i < 65536) {
        wprep_one<256, 128>(W2, Wt2, i - 32768);  // W2: 256x128
    } else if (i < 73728) {
        wprep_one<128, 64>(W3, Wt3, i - 65536);   // W3: 128x64
    }
}

// ---------------- P0: U0 = bf16(dinv ⊙ x) ----------------
__global__ __launch_bounds__(256) void scale_cvt(const float* __restrict__ x,
                                                 const float* __restrict__ dinv,
                                                 uint32_t* __restrict__ U, long total) {
    long i = (long)blockIdx.x * 256 + threadIdx.x;
    if (i >= total) return;
    int row = (int)(i >> 6);
    float2 v = ((const float2*)x)[i];
    float d = dinv[row];
    U[i] = packbf(d * v.x, d * v.y);
}

// ---------------- aggregation, 128 channels (wave per node) ----------------
template <bool BIAS_RELU>
__global__ __launch_bounds__(256) void agg128(const uint32_t* __restrict__ U,
                                              const float* __restrict__ dinv,
                                              const int* __restrict__ row_ptr,
                                              const int* __restrict__ csr_src,
                                              const float* __restrict__ bias,
                                              uint32_t* __restrict__ Out, int N) {
    int wave = threadIdx.x >> 6, lane = threadIdx.x & 63;
    int n = blockIdx.x * 4 + wave;
    if (n >= N) return;
    uint32_t u = U[(long)n * 64 + lane];
    float s0 = bf_lo(u), s1 = bf_hi(u);
    int e0 = row_ptr[n], e1 = row_ptr[n + 1];
    for (int e = e0; e < e1; e += 8) {
        int idx[8];
        uint32_t uu[8];
#pragma unroll
        for (int j = 0; j < 8; ++j) {
            int ee = e + j; if (ee > e1 - 1) ee = e1 - 1;
            idx[j] = csr_src[ee];
        }
#pragma unroll
        for (int j = 0; j < 8; ++j) uu[j] = U[(long)idx[j] * 64 + lane];
#pragma unroll
        for (int j = 0; j < 8; ++j) {
            float m = (e + j < e1) ? 1.f : 0.f;
            s0 += m * bf_lo(uu[j]);
            s1 += m * bf_hi(uu[j]);
        }
    }
    float d = dinv[n];
    float r0 = d * s0, r1 = d * s1;
    if constexpr (BIAS_RELU) {
        r0 = fmaxf(r0 + bias[2 * lane], 0.f);
        r1 = fmaxf(r1 + bias[2 * lane + 1], 0.f);
    }
    Out[(long)n * 64 + lane] = packbf(r0, r1);
}

// ---------------- agg 64 channels + bias/relu + linear head ----------------
__global__ __launch_bounds__(256) void agg64_head(const uint16_t* __restrict__ U,
                                                  const float* __restrict__ dinv,
                                                  const int* __restrict__ row_ptr,
                                                  const int* __restrict__ csr_src,
                                                  const float* __restrict__ b3,
                                                  const float* __restrict__ Wl,
                                                  const float* __restrict__ bl,
                                                  float* __restrict__ out, int N) {
    int wave = threadIdx.x >> 6, lane = threadIdx.x & 63;
    int n = blockIdx.x * 4 + wave;
    if (n >= N) return;
    float s = bf_s(U[(long)n * 64 + lane]);
    int e0 = row_ptr[n], e1 = row_ptr[n + 1];
    for (int e = e0; e < e1; e += 8) {
        int idx[8];
        uint16_t uu[8];
#pragma unroll
        for (int j = 0; j < 8; ++j) {
            int ee = e + j; if (ee > e1 - 1) ee = e1 - 1;
            idx[j] = csr_src[ee];
        }
#pragma unroll
        for (int j = 0; j < 8; ++j) uu[j] = U[(long)idx[j] * 64 + lane];
#pragma unroll
        for (int j = 0; j < 8; ++j) {
            float m = (e + j < e1) ? 1.f : 0.f;
            s += m * bf_s(uu[j]);
        }
    }
    float h = fmaxf(dinv[n] * s + b3[lane], 0.f);
    float v = h * Wl[lane];
#pragma unroll
    for (int off = 32; off; off >>= 1) v += __shfl_xor(v, off);
    if (lane == 0) out[n] = v + bl[0];
}

// ---------------- MFMA GEMM (transposed): D = Wt_tile · X^T ----------------
// Y[N,M](bf16) = A[N,K](bf16) @ Wt[M,K](bf16), computed as Y^T per tile.
// Operand swap: A-operand = Wt tile from LDS, B-operand = X rows from global.
// (A/B fragments have identical lane layout: l31 -> row/col, 8*lhi+j -> k.)
// C/D: col=l31 -> NODE (fixed per lane!), row=(r&3)+8*(r>>2)+4*lhi -> m.
// Epilogue: per lane, 4 consecutive m per reg-group -> packed 8B stores off
// one base pointer (immediate offsets), one dinv load per thread.
// LDS rows stride SD=72 shorts (36 dw ≡ 4 mod 32 -> b128 reads conflict-free,
// measured 0 conflicts R3-R5).
template <int K, int M, bool BIAS_RELU, bool SCALE_OUT>
__global__ __launch_bounds__(256, 2) void gemm_mfma(const uint16_t* __restrict__ A,
                                                    const uint16_t* __restrict__ Wt,
                                                    const float* __restrict__ bias,
                                                    const float* __restrict__ dinv,
                                                    uint16_t* __restrict__ Y, int N) {
    constexpr int NT = M / 32;      // m tiles per wave
    constexpr int NK = K / 16;      // k-steps total
    constexpr int KC = 64;          // K-chunk in LDS
    constexpr int SD = KC + 8;      // LDS row stride (shorts)
    constexpr int CPR = KC / 8;     // 16B chunks per LDS row (=8)
    __shared__ short wl[M * SD];

    int t = threadIdx.x;
    int wave = t >> 6, lane = t & 63;
    int l31 = lane & 31, lhi = lane >> 5;
    long row0 = (long)blockIdx.x * 128 + wave * 32;

    // X fragments (B-operand) for the whole K, loaded upfront
    bf16x8 afrag[NK];
    {
        long arow = row0 + l31; if (arow > N - 1) arow = N - 1;
        const uint16_t* ap = A + arow * K + lhi * 8;
#pragma unroll
        for (int s = 0; s < NK; ++s)
            afrag[s] = *(const bf16x8*)(ap + s * 16);
    }

    f32x16 acc[NT];
#pragma unroll
    for (int c = 0; c < NT; ++c)
#pragma unroll
        for (int r = 0; r < 16; ++r) acc[c][r] = 0.f;

    int r0 = t / CPR, cc8 = (t % CPR) * 8;
    for (int kc0 = 0; kc0 < K; kc0 += KC) {
        // stage Wt[:, kc0:kc0+KC] -> wl (16B vector copies)
#pragma unroll
        for (int r = r0; r < M; r += 256 / CPR)
            *(bf16x8*)(wl + r * SD + cc8) = *(const bf16x8*)(Wt + (long)r * K + kc0 + cc8);
        __syncthreads();
#pragma unroll
        for (int s = 0; s < KC / 16; ++s) {
            const short* bp = wl + l31 * SD + s * 16 + lhi * 8;
#pragma unroll
            for (int c = 0; c < NT; ++c) {
                bf16x8 wfrag = *(const bf16x8*)(bp + c * 32 * SD);
                // swapped: A-operand = W fragment, B-operand = X fragment
                acc[c] = __builtin_amdgcn_mfma_f32_32x32x16_bf16(
                    wfrag, afrag[kc0 / 16 + s], acc[c], 0, 0, 0);
            }
        }
        __syncthreads();
    }

    // epilogue: lane owns node row0+l31; m runs of 4 -> 8B packed stores
    long node = row0 + l31;
    bool ok = node < N;
    long nclamp = ok ? node : (N - 1);
    float dn = SCALE_OUT ? dinv[nclamp] : 1.f;
    uint16_t* yp = Y + nclamp * M;
#pragma unroll
    for (int c = 0; c < NT; ++c) {
#pragma unroll
        for (int g = 0; g < 4; ++g) {
            int m0 = c * 32 + g * 8 + 4 * lhi;
            float v[4];
#pragma unroll
            for (int j = 0; j < 4; ++j) {
                float x = acc[c][g * 4 + j];
                if constexpr (BIAS_RELU) x = fmaxf(x + bias[m0 + j], 0.f);
                if constexpr (SCALE_OUT) x *= dn;
                v[j] = x;
            }
            if (ok) {
                uint2 pk; pk.x = packbf(v[0], v[1]); pk.y = packbf(v[2], v[3]);
                *(uint2*)(yp + m0) = pk;
            }
        }
    }
}

extern "C" void kernel_launch(void* const* d_in, const int* in_sizes, int n_in,
                              void* d_out, int out_size, void* d_ws, size_t ws_size,
                              hipStream_t stream) {
    const float* x  = (const float*)d_in[0];
    const int* edge = (const int*)d_in[1];
    const float* W1 = (const float*)d_in[2];
    const float* b1 = (const float*)d_in[3];
    const float* W2 = (const float*)d_in[4];
    const float* b2 = (const float*)d_in[5];
    const float* W3 = (const float*)d_in[6];
    const float* b3 = (const float*)d_in[7];
    const float* Wl = (const float*)d_in[8];
    const float* bl = (const float*)d_in[9];
    float* out = (float*)d_out;

    int N = in_sizes[0] / 128;   // 100000
    int E = in_sizes[1] / 2;     // 800000
    const int* src = edge;
    const int* dst = edge + E;

    char* ws = (char*)d_ws;
    size_t off = 0;
    auto alloc = [&](size_t bytes) {
        void* p = ws + off;
        off += (bytes + 255) & ~(size_t)255;
        return p;
    };
    int*      cnt     = (int*)     alloc((size_t)N * 4);
    int*      row_ptr = (int*)     alloc((size_t)(N + 1) * 4);
    float*    dinv    = (float*)   alloc((size_t)N * 4);
    int*      csr_src = (int*)     alloc((size_t)E * 4);
    int*      bsum    = (int*)     alloc(128 * 4);
    uint16_t* Wt1     = (uint16_t*)alloc(256 * 128 * 2);
    uint16_t* Wt2     = (uint16_t*)alloc(128 * 256 * 2);
    uint16_t* Wt3     = (uint16_t*)alloc(64 * 128 * 2);
    uint32_t* B_a     = (uint32_t*)alloc((size_t)N * 64 * 4);    // 128ch bf16
    uint32_t* B_b     = (uint32_t*)alloc((size_t)N * 64 * 4);    // 128ch bf16
    uint32_t* B_c     = (uint32_t*)alloc((size_t)N * 128 * 4);   // 256ch bf16
    (void)ws_size; (void)n_in; (void)out_size;

    int NB = (N + 1023) / 1024;   // 98

    // graph preprocessing (rebuilt every launch; ws is re-poisoned)
    hipMemsetAsync(cnt, 0, (size_t)N * 4, stream);
    hist_kernel<<<(E + 255) / 256, 256, 0, stream>>>(dst, cnt, E);
    dinv_kernel<<<(N + 255) / 256, 256, 0, stream>>>(cnt, dinv, N);
    scan_blk<<<NB, 256, 0, stream>>>(cnt, row_ptr, bsum, N);
    scan_tops<<<1, 128, 0, stream>>>(bsum, NB);
    scan_add<<<NB, 256, 0, stream>>>(row_ptr, bsum, N, E);
    fill_kernel<<<(E + 255) / 256, 256, 0, stream>>>(src, dst, row_ptr, cnt, csr_src, E);
    wprep<<<288, 256, 0, stream>>>(W1, W2, W3, Wt1, Wt2, Wt3);

    // P0
    scale_cvt<<<(int)(((long)N * 64 + 255) / 256), 256, 0, stream>>>(x, dinv, B_a, (long)N * 64);
    // layer 1
    agg128<false><<<(N + 3) / 4, 256, 0, stream>>>(B_a, dinv, row_ptr, csr_src, nullptr, B_b, N);
    gemm_mfma<128, 256, true, false><<<(N + 127) / 128, 256, 0, stream>>>(
        (const uint16_t*)B_b, Wt1, b1, nullptr, (uint16_t*)B_c, N);
    // layer 2
    gemm_mfma<256, 128, false, true><<<(N + 127) / 128, 256, 0, stream>>>(
        (const uint16_t*)B_c, Wt2, nullptr, dinv, (uint16_t*)B_a, N);
    agg128<true><<<(N + 3) / 4, 256, 0, stream>>>(B_a, dinv, row_ptr, csr_src, b2, B_b, N);
    // layer 3
    gemm_mfma<128, 64, false, true><<<(N + 127) / 128, 256, 0, stream>>>(
        (const uint16_t*)B_b, Wt3, nullptr, dinv, (uint16_t*)B_a, N);
    // agg + head
    agg64_head<<<(N + 3) / 4, 256, 0, stream>>>(
        (const uint16_t*)B_a, dinv, row_ptr, csr_src, b3, Wl, bl, out, N);
}

// Round 7
// 383.323 us; speedup vs baseline: 2.6115x; 1.0254x over previous
//
#include <hip/hip_runtime.h>
#include <hip/hip_bf16.h>
#include <stdint.h>

// GCN 3-layer + head, bf16 data path, fp32 accumulate everywhere.
// Identity: Â(XW) = (ÂX)W; aggregate on the narrower side.
// Scaled-space: store ṽ = dinv⊙v (bf16) -> gather loop is a pure row-sum.
// This round: FUSED gemm1+gemm2. H1 = relu(A1@W1+b1) stays in registers
// (bf16-packed), cross-half-wave __shfl_xor(32) redistributes the channel
// blocks so H1 fragments feed gemm2's MFMA directly. Kills H1's 51MB write
// + 26MB read + one dispatch. Arithmetic identical to unfused (H1 passes
// through bf16 either way).

typedef __attribute__((ext_vector_type(8))) short bf16x8;
typedef __attribute__((ext_vector_type(16))) float f32x16;

__device__ __forceinline__ float bf_lo(uint32_t u) {
    union { uint32_t i; float f; } v; v.i = u << 16; return v.f;
}
__device__ __forceinline__ float bf_hi(uint32_t u) {
    union { uint32_t i; float f; } v; v.i = u & 0xffff0000u; return v.f;
}
__device__ __forceinline__ float bf_s(uint16_t h) {
    union { uint32_t i; float f; } v; v.i = ((uint32_t)h) << 16; return v.f;
}
__device__ __forceinline__ uint16_t f2bf(float f) {   // RNE
    union { float f; uint32_t i; } v; v.f = f;
    uint32_t r = v.i + 0x7fffu + ((v.i >> 16) & 1u);
    return (uint16_t)(r >> 16);
}
__device__ __forceinline__ uint32_t packbf(float a, float b) {
    return (uint32_t)f2bf(a) | ((uint32_t)f2bf(b) << 16);
}

// ---------------- graph preprocessing ----------------
__global__ __launch_bounds__(256) void hist_kernel(const int* __restrict__ dst,
                                                   int* __restrict__ cnt, int E) {
    int e = blockIdx.x * 256 + threadIdx.x;
    if (e < E) atomicAdd(&cnt[dst[e]], 1);
}

__global__ __launch_bounds__(256) void dinv_kernel(const int* __restrict__ cnt,
                                                   float* __restrict__ dinv, int N) {
    int i = blockIdx.x * 256 + threadIdx.x;
    if (i < N) dinv[i] = rsqrtf((float)cnt[i] + 1.0f);
}

// 3-phase scan (98 blocks of 1024 elems).
__global__ __launch_bounds__(256) void scan_blk(const int* __restrict__ cnt,
                                                int* __restrict__ row_ptr,
                                                int* __restrict__ bsum, int N) {
    int b = blockIdx.x, t = threadIdx.x;
    int base = b * 1024 + t * 4;
    int v0 = 0, v1 = 0, v2 = 0, v3 = 0;
    if (base + 3 < N) {
        int4 q = *(const int4*)(cnt + base);
        v0 = q.x; v1 = q.y; v2 = q.z; v3 = q.w;
    } else if (base < N) {
        v0 = cnt[base];
        if (base + 1 < N) v1 = cnt[base + 1];
        if (base + 2 < N) v2 = cnt[base + 2];
    }
    int tsum = v0 + v1 + v2 + v3;
    __shared__ int ps[256];
    ps[t] = tsum;
    __syncthreads();
    for (int off = 1; off < 256; off <<= 1) {
        int x = (t >= off) ? ps[t - off] : 0;
        __syncthreads();
        ps[t] += x;
        __syncthreads();
    }
    int ex = (t == 0) ? 0 : ps[t - 1];
    if (t == 255) bsum[b] = ps[255];
    if (base + 3 < N) {
        int4 w; w.x = ex; w.y = ex + v0; w.z = ex + v0 + v1; w.w = ex + v0 + v1 + v2;
        *(int4*)(row_ptr + base) = w;
    } else if (base < N) {
        row_ptr[base] = ex;
        if (base + 1 < N) row_ptr[base + 1] = ex + v0;
        if (base + 2 < N) row_ptr[base + 2] = ex + v0 + v1;
    }
}

__global__ __launch_bounds__(128) void scan_tops(int* __restrict__ bsum, int NB) {
    __shared__ int ps[128];
    int t = threadIdx.x;
    int v = (t < NB) ? bsum[t] : 0;
    ps[t] = v;
    __syncthreads();
    for (int off = 1; off < 128; off <<= 1) {
        int x = (t >= off) ? ps[t - off] : 0;
        __syncthreads();
        ps[t] += x;
        __syncthreads();
    }
    if (t < NB) bsum[t] = (t == 0) ? 0 : ps[t - 1];
}

__global__ __launch_bounds__(256) void scan_add(int* __restrict__ row_ptr,
                                                const int* __restrict__ bsum,
                                                int N, int E) {
    int b = blockIdx.x, t = threadIdx.x;
    int base = b * 1024 + t * 4;
    int off = bsum[b];
    if (base + 3 < N) {
        int4 q = *(int4*)(row_ptr + base);
        q.x += off; q.y += off; q.z += off; q.w += off;
        *(int4*)(row_ptr + base) = q;
    } else {
        for (int i = 0; i < 4; ++i)
            if (base + i < N) row_ptr[base + i] += off;
    }
    if (b == 0 && t == 0) row_ptr[N] = E;
}

__global__ __launch_bounds__(256) void fill_kernel(const int* __restrict__ src,
                                                   const int* __restrict__ dst,
                                                   const int* __restrict__ row_ptr,
                                                   int* __restrict__ cnt,
                                                   int* __restrict__ csr_src, int E) {
    int e = blockIdx.x * 256 + threadIdx.x;
    if (e < E) {
        int d = dst[e];
        int old = atomicSub(&cnt[d], 1);
        csr_src[row_ptr[d + 1] - old] = src[e];
    }
}

// ---------------- wprep: W (fp32, [k][m]) -> Wt (bf16, [m][k]) ----------------
template <int K, int M>
__device__ __forceinline__ void wprep_one(const float* __restrict__ W,
                                          uint16_t* __restrict__ Wt, int j) {
    int m = j / K, k = j % K;
    Wt[j] = f2bf(W[k * M + m]);
}
__global__ __launch_bounds__(256) void wprep(const float* __restrict__ W1,
                                             const float* __restrict__ W2,
                                             const float* __restrict__ W3,
                                             uint16_t* __restrict__ Wt1,
                                             uint16_t* __restrict__ Wt2,
                                             uint16_t* __restrict__ Wt3) {
    int i = blockIdx.x * 256 + threadIdx.x;
    if (i < 32768) {
        wprep_one<128, 256>(W1, Wt1, i);          // W1: 128x256
    } else if (i < 65536) {
        wprep_one<256, 128>(W2, Wt2, i - 32768);  // W2: 256x128
    } else if (i < 73728) {
        wprep_one<128, 64>(W3, Wt3, i - 65536);   // W3: 128x64
    }
}

// ---------------- P0: U0 = bf16(dinv ⊙ x) ----------------
__global__ __launch_bounds__(256) void scale_cvt(const float* __restrict__ x,
                                                 const float* __restrict__ dinv,
                                                 uint32_t* __restrict__ U, long total) {
    long i = (long)blockIdx.x * 256 + threadIdx.x;
    if (i >= total) return;
    int row = (int)(i >> 6);
    float2 v = ((const float2*)x)[i];
    float d = dinv[row];
    U[i] = packbf(d * v.x, d * v.y);
}

// ---------------- aggregation, 128 channels (wave per node) ----------------
template <bool BIAS_RELU>
__global__ __launch_bounds__(256) void agg128(const uint32_t* __restrict__ U,
                                              const float* __restrict__ dinv,
                                              const int* __restrict__ row_ptr,
                                              const int* __restrict__ csr_src,
                                              const float* __restrict__ bias,
                                              uint32_t* __restrict__ Out, int N) {
    int wave = threadIdx.x >> 6, lane = threadIdx.x & 63;
    int n = blockIdx.x * 4 + wave;
    if (n >= N) return;
    uint32_t u = U[(long)n * 64 + lane];
    float s0 = bf_lo(u), s1 = bf_hi(u);
    int e0 = row_ptr[n], e1 = row_ptr[n + 1];
    for (int e = e0; e < e1; e += 8) {
        int idx[8];
        uint32_t uu[8];
#pragma unroll
        for (int j = 0; j < 8; ++j) {
            int ee = e + j; if (ee > e1 - 1) ee = e1 - 1;
            idx[j] = csr_src[ee];
        }
#pragma unroll
        for (int j = 0; j < 8; ++j) uu[j] = U[(long)idx[j] * 64 + lane];
#pragma unroll
        for (int j = 0; j < 8; ++j) {
            float m = (e + j < e1) ? 1.f : 0.f;
            s0 += m * bf_lo(uu[j]);
            s1 += m * bf_hi(uu[j]);
        }
    }
    float d = dinv[n];
    float r0 = d * s0, r1 = d * s1;
    if constexpr (BIAS_RELU) {
        r0 = fmaxf(r0 + bias[2 * lane], 0.f);
        r1 = fmaxf(r1 + bias[2 * lane + 1], 0.f);
    }
    Out[(long)n * 64 + lane] = packbf(r0, r1);
}

// ---------------- agg 64 channels + bias/relu + linear head ----------------
__global__ __launch_bounds__(256) void agg64_head(const uint16_t* __restrict__ U,
                                                  const float* __restrict__ dinv,
                                                  const int* __restrict__ row_ptr,
                                                  const int* __restrict__ csr_src,
                                                  const float* __restrict__ b3,
                                                  const float* __restrict__ Wl,
                                                  const float* __restrict__ bl,
                                                  float* __restrict__ out, int N) {
    int wave = threadIdx.x >> 6, lane = threadIdx.x & 63;
    int n = blockIdx.x * 4 + wave;
    if (n >= N) return;
    float s = bf_s(U[(long)n * 64 + lane]);
    int e0 = row_ptr[n], e1 = row_ptr[n + 1];
    for (int e = e0; e < e1; e += 8) {
        int idx[8];
        uint16_t uu[8];
#pragma unroll
        for (int j = 0; j < 8; ++j) {
            int ee = e + j; if (ee > e1 - 1) ee = e1 - 1;
            idx[j] = csr_src[ee];
        }
#pragma unroll
        for (int j = 0; j < 8; ++j) uu[j] = U[(long)idx[j] * 64 + lane];
#pragma unroll
        for (int j = 0; j < 8; ++j) {
            float m = (e + j < e1) ? 1.f : 0.f;
            s += m * bf_s(uu[j]);
        }
    }
    float h = fmaxf(dinv[n] * s + b3[lane], 0.f);
    float v = h * Wl[lane];
#pragma unroll
    for (int off = 32; off; off >>= 1) v += __shfl_xor(v, off);
    if (lane == 0) out[n] = v + bl[0];
}

// ---------------- FUSED gemm1+gemm2 (transposed MFMA, swapped operands) ----------------
// U2[N,128] = dinv ⊙ ( relu(A1[N,128] @ W1 + b1) @ W2 )
// Per block: 128 nodes (4 waves × 32). Phase 1: acc1 = Wt1·A1^T (lane owns
// node l31; m-values at (r&3)+8(r>>2)+4lhi + 32c). Pack H1 to bf16-pair u32s
// pk[16][2] per quad i=c*4+g covering channel block b=2i+lhi (4 ch).
// Phase 2 B-frag for k-step s needs blocks {4s+2lhi local-or-partner}:
//   local idx 2s+lhi, partner's via shfl_xor(32) of idx 2s+1-lhi.
// Then acc2 = Wt2·H1^T; epilogue scales by dinv, packed 8B stores.
__global__ __launch_bounds__(256, 2) void gemm_fused12(const uint16_t* __restrict__ A,
                                                       const uint16_t* __restrict__ Wt1,
                                                       const float* __restrict__ b1,
                                                       const uint16_t* __restrict__ Wt2,
                                                       const float* __restrict__ dinv,
                                                       uint16_t* __restrict__ Y, int N) {
    constexpr int SD = 72;          // LDS row stride in shorts (KC=64 + 8)
    __shared__ short wl[256 * SD];  // 36864 B; reused by both phases

    int t = threadIdx.x;
    int wave = t >> 6, lane = t & 63;
    int l31 = lane & 31, lhi = lane >> 5;
    long row0 = (long)blockIdx.x * 128 + wave * 32;

    // ---- phase 1: K1=128, M1=256 ----
    bf16x8 afrag[8];
    {
        long arow = row0 + l31; if (arow > N - 1) arow = N - 1;
        const uint16_t* ap = A + arow * 128 + lhi * 8;
#pragma unroll
        for (int s = 0; s < 8; ++s)
            afrag[s] = *(const bf16x8*)(ap + s * 16);
    }

    f32x16 acc1[8];
#pragma unroll
    for (int c = 0; c < 8; ++c)
#pragma unroll
        for (int r = 0; r < 16; ++r) acc1[c][r] = 0.f;

    int r0 = t / 8, cc8 = (t % 8) * 8;
    for (int kc0 = 0; kc0 < 128; kc0 += 64) {
#pragma unroll
        for (int r = r0; r < 256; r += 32)
            *(bf16x8*)(wl + r * SD + cc8) = *(const bf16x8*)(Wt1 + (long)r * 128 + kc0 + cc8);
        __syncthreads();
#pragma unroll
        for (int s = 0; s < 4; ++s) {
            const short* bp = wl + l31 * SD + s * 16 + lhi * 8;
#pragma unroll
            for (int c = 0; c < 8; ++c) {
                bf16x8 wfrag = *(const bf16x8*)(bp + c * 32 * SD);
                acc1[c] = __builtin_amdgcn_mfma_f32_32x32x16_bf16(
                    wfrag, afrag[kc0 / 16 + s], acc1[c], 0, 0, 0);
            }
        }
        __syncthreads();
    }

    // ---- H1 = relu(acc1 + b1), packed bf16 pairs: pk[i][2], i=c*4+g ----
    uint32_t pk[32][2];
#pragma unroll
    for (int c = 0; c < 8; ++c) {
#pragma unroll
        for (int g = 0; g < 4; ++g) {
            int m0 = c * 32 + g * 8 + 4 * lhi;
            float4 bv = *(const float4*)(b1 + m0);
            float v0 = fmaxf(acc1[c][g * 4 + 0] + bv.x, 0.f);
            float v1 = fmaxf(acc1[c][g * 4 + 1] + bv.y, 0.f);
            float v2 = fmaxf(acc1[c][g * 4 + 2] + bv.z, 0.f);
            float v3 = fmaxf(acc1[c][g * 4 + 3] + bv.w, 0.f);
            pk[c * 4 + g][0] = packbf(v0, v1);
            pk[c * 4 + g][1] = packbf(v2, v3);
        }
    }

    // ---- phase 2: K2=256, M2=128; B-frags assembled via shfl_xor(32) ----
    f32x16 acc2[4];
#pragma unroll
    for (int c = 0; c < 4; ++c)
#pragma unroll
        for (int r = 0; r < 16; ++r) acc2[c][r] = 0.f;

    for (int kc0 = 0; kc0 < 256; kc0 += 64) {
#pragma unroll
        for (int r = r0; r < 128; r += 32)
            *(bf16x8*)(wl + r * SD + cc8) = *(const bf16x8*)(Wt2 + (long)r * 256 + kc0 + cc8);
        __syncthreads();
#pragma unroll
        for (int sl = 0; sl < 4; ++sl) {
            const int s = kc0 / 16 + sl;           // global k-step, compile-time per unroll
            // assemble H1 fragment for k = 16s + 8*lhi + 0..7
            uint32_t send0 = lhi ? pk[2 * s][0] : pk[2 * s + 1][0];
            uint32_t send1 = lhi ? pk[2 * s][1] : pk[2 * s + 1][1];
            uint32_t rcv0 = __shfl_xor(send0, 32);
            uint32_t rcv1 = __shfl_xor(send1, 32);
            uint32_t lc0 = lhi ? pk[2 * s + 1][0] : pk[2 * s][0];
            uint32_t lc1 = lhi ? pk[2 * s + 1][1] : pk[2 * s][1];
            union { uint32_t u[4]; bf16x8 v; } hf;
            hf.u[0] = lhi ? rcv0 : lc0;
            hf.u[1] = lhi ? rcv1 : lc1;
            hf.u[2] = lhi ? lc0 : rcv0;
            hf.u[3] = lhi ? lc1 : rcv1;
            const short* bp = wl + l31 * SD + sl * 16 + lhi * 8;
#pragma unroll
            for (int c = 0; c < 4; ++c) {
                bf16x8 wfrag = *(const bf16x8*)(bp + c * 32 * SD);
                acc2[c] = __builtin_amdgcn_mfma_f32_32x32x16_bf16(
                    wfrag, hf.v, acc2[c], 0, 0, 0);
            }
        }
        __syncthreads();
    }

    // ---- epilogue: U2 = dinv * acc2, packed 8B stores ----
    long node = row0 + l31;
    bool ok = node < N;
    long nclamp = ok ? node : (N - 1);
    float dn = dinv[nclamp];
    uint16_t* yp = Y + nclamp * 128;
#pragma unroll
    for (int c = 0; c < 4; ++c) {
#pragma unroll
        for (int g = 0; g < 4; ++g) {
            int m0 = c * 32 + g * 8 + 4 * lhi;
            float v0 = acc2[c][g * 4 + 0] * dn;
            float v1 = acc2[c][g * 4 + 1] * dn;
            float v2 = acc2[c][g * 4 + 2] * dn;
            float v3 = acc2[c][g * 4 + 3] * dn;
            if (ok) {
                uint2 pko; pko.x = packbf(v0, v1); pko.y = packbf(v2, v3);
                *(uint2*)(yp + m0) = pko;
            }
        }
    }
}

// ---------------- MFMA GEMM (transposed), for layer 3 ----------------
template <int K, int M, bool BIAS_RELU, bool SCALE_OUT>
__global__ __launch_bounds__(256, 2) void gemm_mfma(const uint16_t* __restrict__ A,
                                                    const uint16_t* __restrict__ Wt,
                                                    const float* __restrict__ bias,
                                                    const float* __restrict__ dinv,
                                                    uint16_t* __restrict__ Y, int N) {
    constexpr int NT = M / 32;
    constexpr int NK = K / 16;
    constexpr int KC = 64;
    constexpr int SD = KC + 8;
    constexpr int CPR = KC / 8;
    __shared__ short wl[M * SD];

    int t = threadIdx.x;
    int wave = t >> 6, lane = t & 63;
    int l31 = lane & 31, lhi = lane >> 5;
    long row0 = (long)blockIdx.x * 128 + wave * 32;

    bf16x8 afrag[NK];
    {
        long arow = row0 + l31; if (arow > N - 1) arow = N - 1;
        const uint16_t* ap = A + arow * K + lhi * 8;
#pragma unroll
        for (int s = 0; s < NK; ++s)
            afrag[s] = *(const bf16x8*)(ap + s * 16);
    }

    f32x16 acc[NT];
#pragma unroll
    for (int c = 0; c < NT; ++c)
#pragma unroll
        for (int r = 0; r < 16; ++r) acc[c][r] = 0.f;

    int r0 = t / CPR, cc8 = (t % CPR) * 8;
    for (int kc0 = 0; kc0 < K; kc0 += KC) {
#pragma unroll
        for (int r = r0; r < M; r += 256 / CPR)
            *(bf16x8*)(wl + r * SD + cc8) = *(const bf16x8*)(Wt + (long)r * K + kc0 + cc8);
        __syncthreads();
#pragma unroll
        for (int s = 0; s < KC / 16; ++s) {
            const short* bp = wl + l31 * SD + s * 16 + lhi * 8;
#pragma unroll
            for (int c = 0; c < NT; ++c) {
                bf16x8 wfrag = *(const bf16x8*)(bp + c * 32 * SD);
                acc[c] = __builtin_amdgcn_mfma_f32_32x32x16_bf16(
                    wfrag, afrag[kc0 / 16 + s], acc[c], 0, 0, 0);
            }
        }
        __syncthreads();
    }

    long node = row0 + l31;
    bool ok = node < N;
    long nclamp = ok ? node : (N - 1);
    float dn = SCALE_OUT ? dinv[nclamp] : 1.f;
    uint16_t* yp = Y + nclamp * M;
#pragma unroll
    for (int c = 0; c < NT; ++c) {
#pragma unroll
        for (int g = 0; g < 4; ++g) {
            int m0 = c * 32 + g * 8 + 4 * lhi;
            float v[4];
#pragma unroll
            for (int j = 0; j < 4; ++j) {
                float x = acc[c][g * 4 + j];
                if constexpr (BIAS_RELU) x = fmaxf(x + bias[m0 + j], 0.f);
                if constexpr (SCALE_OUT) x *= dn;
                v[j] = x;
            }
            if (ok) {
                uint2 pk; pk.x = packbf(v[0], v[1]); pk.y = packbf(v[2], v[3]);
                *(uint2*)(yp + m0) = pk;
            }
        }
    }
}

extern "C" void kernel_launch(void* const* d_in, const int* in_sizes, int n_in,
                              void* d_out, int out_size, void* d_ws, size_t ws_size,
                              hipStream_t stream) {
    const float* x  = (const float*)d_in[0];
    const int* edge = (const int*)d_in[1];
    const float* W1 = (const float*)d_in[2];
    const float* b1 = (const float*)d_in[3];
    const float* W2 = (const float*)d_in[4];
    const float* b2 = (const float*)d_in[5];
    const float* W3 = (const float*)d_in[6];
    const float* b3 = (const float*)d_in[7];
    const float* Wl = (const float*)d_in[8];
    const float* bl = (const float*)d_in[9];
    float* out = (float*)d_out;

    int N = in_sizes[0] / 128;   // 100000
    int E = in_sizes[1] / 2;     // 800000
    const int* src = edge;
    const int* dst = edge + E;

    char* ws = (char*)d_ws;
    size_t off = 0;
    auto alloc = [&](size_t bytes) {
        void* p = ws + off;
        off += (bytes + 255) & ~(size_t)255;
        return p;
    };
    int*      cnt     = (int*)     alloc((size_t)N * 4);
    int*      row_ptr = (int*)     alloc((size_t)(N + 1) * 4);
    float*    dinv    = (float*)   alloc((size_t)N * 4);
    int*      csr_src = (int*)     alloc((size_t)E * 4);
    int*      bsum    = (int*)     alloc(128 * 4);
    uint16_t* Wt1     = (uint16_t*)alloc(256 * 128 * 2);
    uint16_t* Wt2     = (uint16_t*)alloc(128 * 256 * 2);
    uint16_t* Wt3     = (uint16_t*)alloc(64 * 128 * 2);
    uint32_t* B_a     = (uint32_t*)alloc((size_t)N * 64 * 4);    // 128ch bf16
    uint32_t* B_b     = (uint32_t*)alloc((size_t)N * 64 * 4);    // 128ch bf16
    (void)ws_size; (void)n_in; (void)out_size;

    int NB = (N + 1023) / 1024;   // 98

    // graph preprocessing (rebuilt every launch; ws is re-poisoned)
    hipMemsetAsync(cnt, 0, (size_t)N * 4, stream);
    hist_kernel<<<(E + 255) / 256, 256, 0, stream>>>(dst, cnt, E);
    dinv_kernel<<<(N + 255) / 256, 256, 0, stream>>>(cnt, dinv, N);
    scan_blk<<<NB, 256, 0, stream>>>(cnt, row_ptr, bsum, N);
    scan_tops<<<1, 128, 0, stream>>>(bsum, NB);
    scan_add<<<NB, 256, 0, stream>>>(row_ptr, bsum, N, E);
    fill_kernel<<<(E + 255) / 256, 256, 0, stream>>>(src, dst, row_ptr, cnt, csr_src, E);
    wprep<<<288, 256, 0, stream>>>(W1, W2, W3, Wt1, Wt2, Wt3);

    // P0
    scale_cvt<<<(int)(((long)N * 64 + 255) / 256), 256, 0, stream>>>(x, dinv, B_a, (long)N * 64);
    // layer 1 aggregation
    agg128<false><<<(N + 3) / 4, 256, 0, stream>>>(B_a, dinv, row_ptr, csr_src, nullptr, B_b, N);
    // fused: U2 = dinv ⊙ (relu(A1@W1+b1) @ W2)
    gemm_fused12<<<(N + 127) / 128, 256, 0, stream>>>(
        (const uint16_t*)B_b, Wt1, b1, Wt2, dinv, (uint16_t*)B_a, N);
    // layer 2 aggregation
    agg128<true><<<(N + 3) / 4, 256, 0, stream>>>(B_a, dinv, row_ptr, csr_src, b2, B_b, N);
    // layer 3 GEMM
    gemm_mfma<128, 64, false, true><<<(N + 127) / 128, 256, 0, stream>>>(
        (const uint16_t*)B_b, Wt3, nullptr, dinv, (uint16_t*)B_a, N);
    // agg + head
    agg64_head<<<(N + 3) / 4, 256, 0, stream>>>(
        (const uint16_t*)B_a, dinv, row_ptr, csr_src, b3, Wl, bl, out, N);
}

// Round 8
// 381.943 us; speedup vs baseline: 2.6209x; 1.0036x over previous
//
#include <hip/hip_runtime.h>
#include <hip/hip_bf16.h>
#include <stdint.h>

// GCN 3-layer + head, bf16 data path, fp32 accumulate everywhere.
// Identity: Â(XW) = (ÂX)W; aggregate on the narrower side.
// Scaled-space: store ṽ = dinv⊙v (bf16) -> gather loop is a pure row-sum.
// R8: (a) fused gemm12 restructured to avoid register spill (phase-1 in two
// c-halves reusing one 64-AGPR accumulator; weights still staged once) ->
// 2 waves/SIMD, no scratch traffic. (b) csr_src pre-warmed via memset so
// fill's random 4B scatters hit L2-resident lines (kills 58MB->~6MB write).

typedef __attribute__((ext_vector_type(8))) short bf16x8;
typedef __attribute__((ext_vector_type(16))) float f32x16;

__device__ __forceinline__ float bf_lo(uint32_t u) {
    union { uint32_t i; float f; } v; v.i = u << 16; return v.f;
}
__device__ __forceinline__ float bf_hi(uint32_t u) {
    union { uint32_t i; float f; } v; v.i = u & 0xffff0000u; return v.f;
}
__device__ __forceinline__ float bf_s(uint16_t h) {
    union { uint32_t i; float f; } v; v.i = ((uint32_t)h) << 16; return v.f;
}
__device__ __forceinline__ uint16_t f2bf(float f) {   // RNE
    union { float f; uint32_t i; } v; v.f = f;
    uint32_t r = v.i + 0x7fffu + ((v.i >> 16) & 1u);
    return (uint16_t)(r >> 16);
}
__device__ __forceinline__ uint32_t packbf(float a, float b) {
    return (uint32_t)f2bf(a) | ((uint32_t)f2bf(b) << 16);
}

// ---------------- graph preprocessing ----------------
__global__ __launch_bounds__(256) void hist_kernel(const int* __restrict__ dst,
                                                   int* __restrict__ cnt, int E) {
    int e = blockIdx.x * 256 + threadIdx.x;
    if (e < E) atomicAdd(&cnt[dst[e]], 1);
}

__global__ __launch_bounds__(256) void dinv_kernel(const int* __restrict__ cnt,
                                                   float* __restrict__ dinv, int N) {
    int i = blockIdx.x * 256 + threadIdx.x;
    if (i < N) dinv[i] = rsqrtf((float)cnt[i] + 1.0f);
}

// 3-phase scan (98 blocks of 1024 elems).
__global__ __launch_bounds__(256) void scan_blk(const int* __restrict__ cnt,
                                                int* __restrict__ row_ptr,
                                                int* __restrict__ bsum, int N) {
    int b = blockIdx.x, t = threadIdx.x;
    int base = b * 1024 + t * 4;
    int v0 = 0, v1 = 0, v2 = 0, v3 = 0;
    if (base + 3 < N) {
        int4 q = *(const int4*)(cnt + base);
        v0 = q.x; v1 = q.y; v2 = q.z; v3 = q.w;
    } else if (base < N) {
        v0 = cnt[base];
        if (base + 1 < N) v1 = cnt[base + 1];
        if (base + 2 < N) v2 = cnt[base + 2];
    }
    int tsum = v0 + v1 + v2 + v3;
    __shared__ int ps[256];
    ps[t] = tsum;
    __syncthreads();
    for (int off = 1; off < 256; off <<= 1) {
        int x = (t >= off) ? ps[t - off] : 0;
        __syncthreads();
        ps[t] += x;
        __syncthreads();
    }
    int ex = (t == 0) ? 0 : ps[t - 1];
    if (t == 255) bsum[b] = ps[255];
    if (base + 3 < N) {
        int4 w; w.x = ex; w.y = ex + v0; w.z = ex + v0 + v1; w.w = ex + v0 + v1 + v2;
        *(int4*)(row_ptr + base) = w;
    } else if (base < N) {
        row_ptr[base] = ex;
        if (base + 1 < N) row_ptr[base + 1] = ex + v0;
        if (base + 2 < N) row_ptr[base + 2] = ex + v0 + v1;
    }
}

__global__ __launch_bounds__(128) void scan_tops(int* __restrict__ bsum, int NB) {
    __shared__ int ps[128];
    int t = threadIdx.x;
    int v = (t < NB) ? bsum[t] : 0;
    ps[t] = v;
    __syncthreads();
    for (int off = 1; off < 128; off <<= 1) {
        int x = (t >= off) ? ps[t - off] : 0;
        __syncthreads();
        ps[t] += x;
        __syncthreads();
    }
    if (t < NB) bsum[t] = (t == 0) ? 0 : ps[t - 1];
}

__global__ __launch_bounds__(256) void scan_add(int* __restrict__ row_ptr,
                                                const int* __restrict__ bsum,
                                                int N, int E) {
    int b = blockIdx.x, t = threadIdx.x;
    int base = b * 1024 + t * 4;
    int off = bsum[b];
    if (base + 3 < N) {
        int4 q = *(int4*)(row_ptr + base);
        q.x += off; q.y += off; q.z += off; q.w += off;
        *(int4*)(row_ptr + base) = q;
    } else {
        for (int i = 0; i < 4; ++i)
            if (base + i < N) row_ptr[base + i] += off;
    }
    if (b == 0 && t == 0) row_ptr[N] = E;
}

__global__ __launch_bounds__(256) void fill_kernel(const int* __restrict__ src,
                                                   const int* __restrict__ dst,
                                                   const int* __restrict__ row_ptr,
                                                   int* __restrict__ cnt,
                                                   int* __restrict__ csr_src, int E) {
    int e = blockIdx.x * 256 + threadIdx.x;
    if (e < E) {
        int d = dst[e];
        int old = atomicSub(&cnt[d], 1);
        csr_src[row_ptr[d + 1] - old] = src[e];
    }
}

// ---------------- wprep: W (fp32, [k][m]) -> Wt (bf16, [m][k]) ----------------
template <int K, int M>
__device__ __forceinline__ void wprep_one(const float* __restrict__ W,
                                          uint16_t* __restrict__ Wt, int j) {
    int m = j / K, k = j % K;
    Wt[j] = f2bf(W[k * M + m]);
}
__global__ __launch_bounds__(256) void wprep(const float* __restrict__ W1,
                                             const float* __restrict__ W2,
                                             const float* __restrict__ W3,
                                             uint16_t* __restrict__ Wt1,
                                             uint16_t* __restrict__ Wt2,
                                             uint16_t* __restrict__ Wt3) {
    int i = blockIdx.x * 256 + threadIdx.x;
    if (i < 32768) {
        wprep_one<128, 256>(W1, Wt1, i);          // W1: 128x256
    } else if (i < 65536) {
        wprep_one<256, 128>(W2, Wt2, i - 32768);  // W2: 256x128
    } else if (i < 73728) {
        wprep_one<128, 64>(W3, Wt3, i - 65536);   // W3: 128x64
    }
}

// ---------------- P0: U0 = bf16(dinv ⊙ x) ----------------
__global__ __launch_bounds__(256) void scale_cvt(const float* __restrict__ x,
                                                 const float* __restrict__ dinv,
                                                 uint32_t* __restrict__ U, long total) {
    long i = (long)blockIdx.x * 256 + threadIdx.x;
    if (i >= total) return;
    int row = (int)(i >> 6);
    float2 v = ((const float2*)x)[i];
    float d = dinv[row];
    U[i] = packbf(d * v.x, d * v.y);
}

// ---------------- aggregation, 128 channels (wave per node) ----------------
template <bool BIAS_RELU>
__global__ __launch_bounds__(256) void agg128(const uint32_t* __restrict__ U,
                                              const float* __restrict__ dinv,
                                              const int* __restrict__ row_ptr,
                                              const int* __restrict__ csr_src,
                                              const float* __restrict__ bias,
                                              uint32_t* __restrict__ Out, int N) {
    int wave = threadIdx.x >> 6, lane = threadIdx.x & 63;
    int n = blockIdx.x * 4 + wave;
    if (n >= N) return;
    uint32_t u = U[(long)n * 64 + lane];
    float s0 = bf_lo(u), s1 = bf_hi(u);
    int e0 = row_ptr[n], e1 = row_ptr[n + 1];
    for (int e = e0; e < e1; e += 8) {
        int idx[8];
        uint32_t uu[8];
#pragma unroll
        for (int j = 0; j < 8; ++j) {
            int ee = e + j; if (ee > e1 - 1) ee = e1 - 1;
            idx[j] = csr_src[ee];
        }
#pragma unroll
        for (int j = 0; j < 8; ++j) uu[j] = U[(long)idx[j] * 64 + lane];
#pragma unroll
        for (int j = 0; j < 8; ++j) {
            float m = (e + j < e1) ? 1.f : 0.f;
            s0 += m * bf_lo(uu[j]);
            s1 += m * bf_hi(uu[j]);
        }
    }
    float d = dinv[n];
    float r0 = d * s0, r1 = d * s1;
    if constexpr (BIAS_RELU) {
        r0 = fmaxf(r0 + bias[2 * lane], 0.f);
        r1 = fmaxf(r1 + bias[2 * lane + 1], 0.f);
    }
    Out[(long)n * 64 + lane] = packbf(r0, r1);
}

// ---------------- agg 64 channels + bias/relu + linear head ----------------
__global__ __launch_bounds__(256) void agg64_head(const uint16_t* __restrict__ U,
                                                  const float* __restrict__ dinv,
                                                  const int* __restrict__ row_ptr,
                                                  const int* __restrict__ csr_src,
                                                  const float* __restrict__ b3,
                                                  const float* __restrict__ Wl,
                                                  const float* __restrict__ bl,
                                                  float* __restrict__ out, int N) {
    int wave = threadIdx.x >> 6, lane = threadIdx.x & 63;
    int n = blockIdx.x * 4 + wave;
    if (n >= N) return;
    float s = bf_s(U[(long)n * 64 + lane]);
    int e0 = row_ptr[n], e1 = row_ptr[n + 1];
    for (int e = e0; e < e1; e += 8) {
        int idx[8];
        uint16_t uu[8];
#pragma unroll
        for (int j = 0; j < 8; ++j) {
            int ee = e + j; if (ee > e1 - 1) ee = e1 - 1;
            idx[j] = csr_src[ee];
        }
#pragma unroll
        for (int j = 0; j < 8; ++j) uu[j] = U[(long)idx[j] * 64 + lane];
#pragma unroll
        for (int j = 0; j < 8; ++j) {
            float m = (e + j < e1) ? 1.f : 0.f;
            s += m * bf_s(uu[j]);
        }
    }
    float h = fmaxf(dinv[n] * s + b3[lane], 0.f);
    float v = h * Wl[lane];
#pragma unroll
    for (int off = 32; off; off >>= 1) v += __shfl_xor(v, off);
    if (lane == 0) out[n] = v + bl[0];
}

// ---------------- FUSED gemm1+gemm2 (transposed MFMA, spill-free) ----------------
// U2[N,128] = dinv ⊙ ( relu(A1[N,128] @ W1 + b1) @ W2 )
// Phase 1 runs in two c-halves (h: output cols [128h,128h+128)) sharing ONE
// 64-AGPR accumulator; Wt1 rows for the half staged with full K=128 in one
// round (each weight staged exactly once). H1 packed to bf16 pairs pk[32][2]
// (chunk i on lane-half lhi covers channels 8i+4lhi..+3 of the lane's node).
// Phase 2: two K-chunks of 128; B-fragments assembled from pk via one
// shfl_xor(32) pair per k-step. Peak regs ~200 -> 2 waves/SIMD, no scratch.
__global__ __launch_bounds__(256, 2) void gemm_fused12(const uint16_t* __restrict__ A,
                                                       const uint16_t* __restrict__ Wt1,
                                                       const float* __restrict__ b1,
                                                       const uint16_t* __restrict__ Wt2,
                                                       const float* __restrict__ dinv,
                                                       uint16_t* __restrict__ Y, int N) {
    constexpr int SD = 136;            // 128 + 8 shorts; 68 dw = 4 mod 32 -> conflict-free
    __shared__ short wl[128 * SD];     // 34,816 B

    int t = threadIdx.x;
    int wave = t >> 6, lane = t & 63;
    int l31 = lane & 31, lhi = lane >> 5;
    long row0 = (long)blockIdx.x * 128 + wave * 32;

    // A fragments (node rows), full K=128
    bf16x8 afrag[8];
    {
        long arow = row0 + l31; if (arow > N - 1) arow = N - 1;
        const uint16_t* ap = A + arow * 128 + lhi * 8;
#pragma unroll
        for (int s = 0; s < 8; ++s)
            afrag[s] = *(const bf16x8*)(ap + s * 16);
    }

    // staging geometry: 128 rows x 16 chunks of 16B
    int srow = t >> 4, scol = (t & 15) * 8;

    uint32_t pk[32][2];

    // ---- phase 1: two c-halves, one 64-AGPR accumulator ----
#pragma unroll
    for (int h = 0; h < 2; ++h) {
#pragma unroll
        for (int i = 0; i < 8; ++i) {
            int r = srow + 16 * i;
            *(bf16x8*)(wl + r * SD + scol) =
                *(const bf16x8*)(Wt1 + (long)(h * 128 + r) * 128 + scol);
        }
        __syncthreads();
        f32x16 acc[4];
#pragma unroll
        for (int c = 0; c < 4; ++c)
#pragma unroll
            for (int r = 0; r < 16; ++r) acc[c][r] = 0.f;
#pragma unroll
        for (int s = 0; s < 8; ++s) {
            const short* bp = wl + l31 * SD + s * 16 + lhi * 8;
#pragma unroll
            for (int c = 0; c < 4; ++c) {
                bf16x8 wfrag = *(const bf16x8*)(bp + c * 32 * SD);
                acc[c] = __builtin_amdgcn_mfma_f32_32x32x16_bf16(
                    wfrag, afrag[s], acc[c], 0, 0, 0);
            }
        }
        __syncthreads();   // before next stage overwrites wl
        // pack H1 = relu(acc + b1): global tile c' = 4h+c
#pragma unroll
        for (int c = 0; c < 4; ++c) {
#pragma unroll
            for (int g = 0; g < 4; ++g) {
                int m0 = (4 * h + c) * 32 + g * 8 + 4 * lhi;
                float4 bv = *(const float4*)(b1 + m0);
                float v0 = fmaxf(acc[c][g * 4 + 0] + bv.x, 0.f);
                float v1 = fmaxf(acc[c][g * 4 + 1] + bv.y, 0.f);
                float v2 = fmaxf(acc[c][g * 4 + 2] + bv.z, 0.f);
                float v3 = fmaxf(acc[c][g * 4 + 3] + bv.w, 0.f);
                pk[(4 * h + c) * 4 + g][0] = packbf(v0, v1);
                pk[(4 * h + c) * 4 + g][1] = packbf(v2, v3);
            }
        }
    }

    // ---- phase 2: K2=256 in two chunks of 128; M2=128 ----
    f32x16 acc2[4];
#pragma unroll
    for (int c = 0; c < 4; ++c)
#pragma unroll
        for (int r = 0; r < 16; ++r) acc2[c][r] = 0.f;

#pragma unroll
    for (int kq = 0; kq < 2; ++kq) {
        const int kc0 = kq * 128;
#pragma unroll
        for (int i = 0; i < 8; ++i) {
            int r = srow + 16 * i;
            *(bf16x8*)(wl + r * SD + scol) =
                *(const bf16x8*)(Wt2 + (long)r * 256 + kc0 + scol);
        }
        __syncthreads();
#pragma unroll
        for (int sl = 0; sl < 8; ++sl) {
            const int s = kc0 / 16 + sl;           // global k-step (compile-time)
            uint32_t send0 = lhi ? pk[2 * s][0] : pk[2 * s + 1][0];
            uint32_t send1 = lhi ? pk[2 * s][1] : pk[2 * s + 1][1];
            uint32_t rcv0 = __shfl_xor(send0, 32);
            uint32_t rcv1 = __shfl_xor(send1, 32);
            uint32_t lc0 = lhi ? pk[2 * s + 1][0] : pk[2 * s][0];
            uint32_t lc1 = lhi ? pk[2 * s + 1][1] : pk[2 * s][1];
            union { uint32_t u[4]; bf16x8 v; } hf;
            hf.u[0] = lhi ? rcv0 : lc0;
            hf.u[1] = lhi ? rcv1 : lc1;
            hf.u[2] = lhi ? lc0 : rcv0;
            hf.u[3] = lhi ? lc1 : rcv1;
            const short* bp = wl + l31 * SD + sl * 16 + lhi * 8;
#pragma unroll
            for (int c = 0; c < 4; ++c) {
                bf16x8 wfrag = *(const bf16x8*)(bp + c * 32 * SD);
                acc2[c] = __builtin_amdgcn_mfma_f32_32x32x16_bf16(
                    wfrag, hf.v, acc2[c], 0, 0, 0);
            }
        }
        __syncthreads();
    }

    // ---- epilogue: U2 = dinv * acc2, packed 8B stores ----
    long node = row0 + l31;
    bool ok = node < N;
    long nclamp = ok ? node : (N - 1);
    float dn = dinv[nclamp];
    uint16_t* yp = Y + nclamp * 128;
#pragma unroll
    for (int c = 0; c < 4; ++c) {
#pragma unroll
        for (int g = 0; g < 4; ++g) {
            int m0 = c * 32 + g * 8 + 4 * lhi;
            float v0 = acc2[c][g * 4 + 0] * dn;
            float v1 = acc2[c][g * 4 + 1] * dn;
            float v2 = acc2[c][g * 4 + 2] * dn;
            float v3 = acc2[c][g * 4 + 3] * dn;
            if (ok) {
                uint2 pko; pko.x = packbf(v0, v1); pko.y = packbf(v2, v3);
                *(uint2*)(yp + m0) = pko;
            }
        }
    }
}

// ---------------- MFMA GEMM (transposed), for layer 3 ----------------
template <int K, int M, bool BIAS_RELU, bool SCALE_OUT>
__global__ __launch_bounds__(256, 2) void gemm_mfma(const uint16_t* __restrict__ A,
                                                    const uint16_t* __restrict__ Wt,
                                                    const float* __restrict__ bias,
                                                    const float* __restrict__ dinv,
                                                    uint16_t* __restrict__ Y, int N) {
    constexpr int NT = M / 32;
    constexpr int NK = K / 16;
    constexpr int KC = 64;
    constexpr int SD = KC + 8;
    constexpr int CPR = KC / 8;
    __shared__ short wl[M * SD];

    int t = threadIdx.x;
    int wave = t >> 6, lane = t & 63;
    int l31 = lane & 31, lhi = lane >> 5;
    long row0 = (long)blockIdx.x * 128 + wave * 32;

    bf16x8 afrag[NK];
    {
        long arow = row0 + l31; if (arow > N - 1) arow = N - 1;
        const uint16_t* ap = A + arow * K + lhi * 8;
#pragma unroll
        for (int s = 0; s < NK; ++s)
            afrag[s] = *(const bf16x8*)(ap + s * 16);
    }

    f32x16 acc[NT];
#pragma unroll
    for (int c = 0; c < NT; ++c)
#pragma unroll
        for (int r = 0; r < 16; ++r) acc[c][r] = 0.f;

    int r0 = t / CPR, cc8 = (t % CPR) * 8;
    for (int kc0 = 0; kc0 < K; kc0 += KC) {
#pragma unroll
        for (int r = r0; r < M; r += 256 / CPR)
            *(bf16x8*)(wl + r * SD + cc8) = *(const bf16x8*)(Wt + (long)r * K + kc0 + cc8);
        __syncthreads();
#pragma unroll
        for (int s = 0; s < KC / 16; ++s) {
            const short* bp = wl + l31 * SD + s * 16 + lhi * 8;
#pragma unroll
            for (int c = 0; c < NT; ++c) {
                bf16x8 wfrag = *(const bf16x8*)(bp + c * 32 * SD);
                acc[c] = __builtin_amdgcn_mfma_f32_32x32x16_bf16(
                    wfrag, afrag[kc0 / 16 + s], acc[c], 0, 0, 0);
            }
        }
        __syncthreads();
    }

    long node = row0 + l31;
    bool ok = node < N;
    long nclamp = ok ? node : (N - 1);
    float dn = SCALE_OUT ? dinv[nclamp] : 1.f;
    uint16_t* yp = Y + nclamp * M;
#pragma unroll
    for (int c = 0; c < NT; ++c) {
#pragma unroll
        for (int g = 0; g < 4; ++g) {
            int m0 = c * 32 + g * 8 + 4 * lhi;
            float v[4];
#pragma unroll
            for (int j = 0; j < 4; ++j) {
                float x = acc[c][g * 4 + j];
                if constexpr (BIAS_RELU) x = fmaxf(x + bias[m0 + j], 0.f);
                if constexpr (SCALE_OUT) x *= dn;
                v[j] = x;
            }
            if (ok) {
                uint2 pk; pk.x = packbf(v[0], v[1]); pk.y = packbf(v[2], v[3]);
                *(uint2*)(yp + m0) = pk;
            }
        }
    }
}

extern "C" void kernel_launch(void* const* d_in, const int* in_sizes, int n_in,
                              void* d_out, int out_size, void* d_ws, size_t ws_size,
                              hipStream_t stream) {
    const float* x  = (const float*)d_in[0];
    const int* edge = (const int*)d_in[1];
    const float* W1 = (const float*)d_in[2];
    const float* b1 = (const float*)d_in[3];
    const float* W2 = (const float*)d_in[4];
    const float* b2 = (const float*)d_in[5];
    const float* W3 = (const float*)d_in[6];
    const float* b3 = (const float*)d_in[7];
    const float* Wl = (const float*)d_in[8];
    const float* bl = (const float*)d_in[9];
    float* out = (float*)d_out;

    int N = in_sizes[0] / 128;   // 100000
    int E = in_sizes[1] / 2;     // 800000
    const int* src = edge;
    const int* dst = edge + E;

    char* ws = (char*)d_ws;
    size_t off = 0;
    auto alloc = [&](size_t bytes) {
        void* p = ws + off;
        off += (bytes + 255) & ~(size_t)255;
        return p;
    };
    int*      cnt     = (int*)     alloc((size_t)N * 4);
    int*      row_ptr = (int*)     alloc((size_t)(N + 1) * 4);
    float*    dinv    = (float*)   alloc((size_t)N * 4);
    int*      csr_src = (int*)     alloc((size_t)E * 4);
    int*      bsum    = (int*)     alloc(128 * 4);
    uint16_t* Wt1     = (uint16_t*)alloc(256 * 128 * 2);
    uint16_t* Wt2     = (uint16_t*)alloc(128 * 256 * 2);
    uint16_t* Wt3     = (uint16_t*)alloc(64 * 128 * 2);
    uint32_t* B_a     = (uint32_t*)alloc((size_t)N * 64 * 4);    // 128ch bf16
    uint32_t* B_b     = (uint32_t*)alloc((size_t)N * 64 * 4);    // 128ch bf16
    (void)ws_size; (void)n_in; (void)out_size;

    int NB = (N + 1023) / 1024;   // 98

    // graph preprocessing (rebuilt every launch; ws is re-poisoned)
    hipMemsetAsync(cnt, 0, (size_t)N * 4, stream);
    hipMemsetAsync(csr_src, 0, (size_t)E * 4, stream);   // pre-warm L2 lines
    hist_kernel<<<(E + 255) / 256, 256, 0, stream>>>(dst, cnt, E);
    dinv_kernel<<<(N + 255) / 256, 256, 0, stream>>>(cnt, dinv, N);
    scan_blk<<<NB, 256, 0, stream>>>(cnt, row_ptr, bsum, N);
    scan_tops<<<1, 128, 0, stream>>>(bsum, NB);
    scan_add<<<NB, 256, 0, stream>>>(row_ptr, bsum, N, E);
    fill_kernel<<<(E + 255) / 256, 256, 0, stream>>>(src, dst, row_ptr, cnt, csr_src, E);
    wprep<<<288, 256, 0, stream>>>(W1, W2, W3, Wt1, Wt2, Wt3);

    // P0
    scale_cvt<<<(int)(((long)N * 64 + 255) / 256), 256, 0, stream>>>(x, dinv, B_a, (long)N * 64);
    // layer 1 aggregation
    agg128<false><<<(N + 3) / 4, 256, 0, stream>>>(B_a, dinv, row_ptr, csr_src, nullptr, B_b, N);
    // fused: U2 = dinv ⊙ (relu(A1@W1+b1) @ W2)
    gemm_fused12<<<(N + 127) / 128, 256, 0, stream>>>(
        (const uint16_t*)B_b, Wt1, b1, Wt2, dinv, (uint16_t*)B_a, N);
    // layer 2 aggregation
    agg128<true><<<(N + 3) / 4, 256, 0, stream>>>(B_a, dinv, row_ptr, csr_src, b2, B_b, N);
    // layer 3 GEMM
    gemm_mfma<128, 64, false, true><<<(N + 127) / 128, 256, 0, stream>>>(
        (const uint16_t*)B_b, Wt3, nullptr, dinv, (uint16_t*)B_a, N);
    // agg + head
    agg64_head<<<(N + 3) / 4, 256, 0, stream>>>(
        (const uint16_t*)B_a, dinv, row_ptr, csr_src, b3, Wl, bl, out, N);
}